// Round 18
// baseline (890.936 us; speedup 1.0000x reference)
//
#include <hip/hip_runtime.h>
#include <math.h>

#define NPTS   20001
#define NREAL  20000
#define EPAD   1200000
#define KK     64
#define RADF   0.1125f

typedef _Float16 half8_t __attribute__((ext_vector_type(8)));
typedef float    floatx4 __attribute__((ext_vector_type(4)));

__device__ __forceinline__ float sgnf(float v){ return v>0.f ? 1.f : (v<0.f ? -1.f : 0.f); }
__device__ __forceinline__ _Float16 lo16(unsigned u){ return __builtin_bit_cast(_Float16, (unsigned short)(u & 0xffffu)); }
__device__ __forceinline__ _Float16 hi16(unsigned u){ return __builtin_bit_cast(_Float16, (unsigned short)(u >> 16)); }
// deterministic fp32 -> packed f16 hi/lo split (hi in low 16 bits).
__device__ __forceinline__ unsigned packf(float v){
  _Float16 h = (_Float16)v;
  _Float16 l = (_Float16)(v - (float)h);
  return (unsigned)__builtin_bit_cast(unsigned short, h)
       | ((unsigned)__builtin_bit_cast(unsigned short, l) << 16);
}

// byte-offset XOR swizzle for [rows][32]-half (64B-row) LDS tiles.
__device__ __forceinline__ void* swzp(void* base, int byteoff){
  return (void*)((char*)base + (byteoff ^ (((byteoff >> 6) & 7) << 4)));
}
__device__ __forceinline__ const void* swzp(const void* base, int byteoff){
  return (const void*)((const char*)base + (byteoff ^ (((byteoff >> 6) & 7) << 4)));
}

// ---------------- CSR build (edge_src is sorted; pad edges have dst==NREAL) ----------------
__global__ void k_find_ereal(const int* __restrict__ dst, int* __restrict__ ereal){
  int lo=0, hi=EPAD;
  while(lo<hi){ int mid=(lo+hi)>>1; if(dst[mid]==NREAL) hi=mid; else lo=mid+1; }
  *ereal = lo;
}

__global__ void k_csr(const int* __restrict__ src, const int* __restrict__ erealp,
                      int* __restrict__ row_start){
  int i = blockIdx.x*blockDim.x + threadIdx.x;
  if(i > NPTS) return;
  int E = *erealp;
  int lo=0, hi=E;
  while(lo<hi){ int mid=(lo+hi)>>1; if(src[mid] < i) lo=mid+1; else hi=mid; }
  row_start[i] = lo;
}

__global__ void k_build_f(const float* __restrict__ feats, float* __restrict__ f){
  int idx = blockIdx.x*blockDim.x + threadIdx.x;
  if(idx >= NPTS*13) return;
  int i = idx/13, c = idx - i*13;
  f[idx] = (c==0) ? 1.f : feats[i*12 + (c-1)];
}

// ---- feature pre-pass: relu + split + pack, once per layer.
__global__ void k_cvtF(const float* __restrict__ x, unsigned* __restrict__ Fp, int total){
  int idx = blockIdx.x*blockDim.x + threadIdx.x;
  if(idx >= total) return;
  Fp[idx] = packf(fmaxf(x[idx], 0.f));
}

// ---------------- per-edge geometry (exact port of ball_to_cube + window) ----------------
__device__ __forceinline__ void edge_geom(float ox, float oy, float oz,
                                          float& win, float& t0, float& t1, float& t2, int& f0p){
  const float eps = 1e-9f;
  float sq = ox*ox + oy*oy + oz*oz;
  float u = 1.f - sq;
  win = fminf(fmaxf(u*u*u, 0.f), 1.f);
  float norm = sqrtf(sq + eps);
  float rxy2 = ox*ox + oy*oy;
  bool polar = (1.25f*oz*oz > rxy2);
  float s_p = sqrtf(3.f*norm/(norm + fabsf(oz) + eps));
  float s_n = norm / sqrtf(rxy2 + eps);
  float s = polar ? s_p : s_n;
  float xc = ox*s, yc = oy*s;
  float zc = polar ? sgnf(oz)*norm : 1.5f*oz;
  if(sq < 1e-12f){ xc = 0.f; yc = 0.f; zc = 0.f; }
  float r = sqrtf(xc*xc + yc*yc + eps);
  bool c1 = fabsf(xc) >= fabsf(yc);
  float xs = (fabsf(xc) < eps) ? eps : xc;
  float ys = (fabsf(yc) < eps) ? eps : yc;
  const float fop = 1.2732395447351628f; // float32(4/pi)
  float a = c1 ? sgnf(xc)*r : sgnf(yc)*r*fop*atanf(xc/ys);
  float b = c1 ? sgnf(xc)*r*fop*atanf(yc/xs) : sgnf(yc)*r;
  if(xc*xc + yc*yc < 1e-12f){ a = 0.f; b = 0.f; }
  float g0 = fminf(fmaxf((a *0.5f+0.5f)*3.f, 0.f), 3.f);
  float g1 = fminf(fmaxf((b *0.5f+0.5f)*3.f, 0.f), 3.f);
  float g2 = fminf(fmaxf((zc*0.5f+0.5f)*3.f, 0.f), 3.f);
  float f00 = floorf(g0), f01 = floorf(g1), f02 = floorf(g2);
  t0 = g0 - f00; t1 = g1 - f01; t2 = g2 - f02;
  f0p = (int)f00 | ((int)f01 << 2) | ((int)f02 << 4);
}

// ---- k_geom: per-edge staged data, computed ONCE (shared by all 4 scatter layers).
__global__ __launch_bounds__(256) void k_geom(const float* __restrict__ pos,
    const int* __restrict__ esrc, const int* __restrict__ edst,
    float4* __restrict__ gw, int4* __restrict__ gmz)
{
  int e = blockIdx.x*blockDim.x + threadIdx.x;
  if(e >= EPAD) return;
  const int sn = esrc[e], d = edst[e];
  const float ox = (pos[d*3+0]-pos[sn*3+0])/RADF;
  const float oy = (pos[d*3+1]-pos[sn*3+1])/RADF;
  const float oz = (pos[d*3+2]-pos[sn*3+2])/RADF;
  float win, t0, t1, t2; int f0p;
  edge_geom(ox, oy, oz, win, t0, t1, t2, f0p);
  const int i0 = f0p & 3, i1 = (f0p>>2) & 3, i2 = f0p >> 4;
  const int X0 = i0 << 4, X1 = ((i0+1)&3) << 4;
  const int Y0 = i1 << 2, Y1 = ((i1+1)&3) << 2;
  const int Z0 = i2, Z1 = (i2+1) & 3;
  const float wx0 = win*(1.f-t0), wx1 = win*t0;
  const float wy0 = 1.f-t1, wy1 = t1;
  const float wz0 = 1.f-t2, wz1 = t2;
  gw[e] = make_float4(wx0*wy0, wx0*wy1, wx1*wy0, wx1*wy1);
  const int p0 = Z0 & 1;
  const float zA = p0 ? wz1 : wz0;                  // weight for parity-0 (even z) cell
  const int   cA = p0 ? Z1 : Z0;                    // even-z cell
  const int   cB = p0 ? Z0 : Z1;                    // odd-z cell
  const int cells0 = (X0|Y0|cA) | ((X0|Y1|cA)<<8) | ((X1|Y0|cA)<<16) | ((X1|Y1|cA)<<24);
  const int cells1 = (X0|Y0|cB) | ((X0|Y1|cB)<<8) | ((X1|Y0|cB)<<16) | ((X1|Y1|cB)<<24);
  gmz[e] = make_int4(__float_as_int(zA), cells0, cells1, d);
}

// ------- MFMA scatter CIN=64 (v7): 64-EDGE PHASES via dual 32-tiles (r17: 124->113us).
template<int OUT3>
__global__ __launch_bounds__(256) void k_scat64m(
    const unsigned* __restrict__ Fp, const float4* __restrict__ gw,
    const int4* __restrict__ gmz, const int* __restrict__ row_start,
    unsigned* __restrict__ B, int node_base,
    const float* __restrict__ W3, float* __restrict__ out)
{
  __shared__ __align__(128) _Float16 Wh0[64*32];
  __shared__ __align__(128) _Float16 Wl0[64*32];
  __shared__ __align__(128) _Float16 Wh1[64*32];
  __shared__ __align__(128) _Float16 Wl1[64*32];
  __shared__ __align__(128) _Float16 Fh0[64*32];
  __shared__ __align__(128) _Float16 Fl0[64*32];
  __shared__ __align__(128) _Float16 Fh1[64*32];
  __shared__ __align__(128) _Float16 Fl1[64*32];
  __shared__ __align__(16) float4 Sq[64];
  __shared__ __align__(16) int4   Smd[64];
  __shared__ float red[16];

  const int tid  = threadIdx.x;
  const int node = node_base + blockIdx.x;
  const int wv   = tid >> 6;
  const int lane = tid & 63;
  const int frow = lane & 15;
  const int fb   = (lane >> 4) << 4;   // frag col byte offset

  floatx4 acc[4];
  #pragma unroll
  for(int nt=0;nt<4;++nt){ acc[nt][0]=0.f; acc[nt][1]=0.f; acc[nt][2]=0.f; acc[nt][3]=0.f; }

  half8_t hz;
  #pragma unroll
  for(int q8=0;q8<8;++q8) hz[q8] = (_Float16)0;

  const int e0 = row_start[node], e1 = row_start[node+1];

  for(int eb = e0; eb < e1; eb += 64){
    const int n = (e1 - eb < 64) ? (e1 - eb) : 64;
    __syncthreads();                       // prior frag + Sq/Smd reads complete
    if(wv == 0){
      int ei = eb + lane; if(ei >= e1) ei = e1 - 1;   // clamp tail (scatter guarded by n)
      Sq[lane]  = gw[ei];
      Smd[lane] = gmz[ei];
    } else {
      for(int j = tid - 64; j < 1024; j += 192){
        if(j < 256)       ((half8_t*)Wh0)[j]       = hz;
        else if(j < 512)  ((half8_t*)Wl0)[j - 256] = hz;
        else if(j < 768)  ((half8_t*)Wh1)[j - 512] = hz;
        else              ((half8_t*)Wl1)[j - 768] = hz;
      }
    }
    __syncthreads();                       // Sq/Smd + zeroed Wt visible
    {
      half8_t h0r, l0r, h1r, l1r;
      #pragma unroll
      for(int j=0;j<8;++j){
        const int d0 = Smd[wv*8 + j].w;
        const unsigned u0 = Fp[(size_t)d0*64 + lane];
        h0r[j] = lo16(u0);
        l0r[j] = hi16(u0);
        const int d1 = Smd[32 + wv*8 + j].w;
        const unsigned u1 = Fp[(size_t)d1*64 + lane];
        h1r[j] = lo16(u1);
        l1r[j] = hi16(u1);
      }
      *(half8_t*)swzp(Fh0, (lane<<6) + (wv<<4)) = h0r;
      *(half8_t*)swzp(Fl0, (lane<<6) + (wv<<4)) = l0r;
      *(half8_t*)swzp(Fh1, (lane<<6) + (wv<<4)) = h1r;
      *(half8_t*)swzp(Fl1, (lane<<6) + (wv<<4)) = l1r;
    }
    if(lane < 16){
      const int ei = wv*16 + lane;         // 4 waves x 16 = 64 edges
      if(ei < n){
        const float4 q  = Sq[ei];
        const int4   md = Smd[ei];
        const float zA = __int_as_float(md.x), zB = 1.f - zA;
        _Float16* Whp = (ei < 32) ? Wh0 : Wh1;
        _Float16* Wlp = (ei < 32) ? Wl0 : Wl1;
        const int ep = ei & 31;
        #pragma unroll
        for(int t=0;t<8;++t){
          const int   cells = (t < 4) ? md.y : md.z;
          const float zz    = (t < 4) ? zA : zB;
          const int   cell  = (cells >> ((t & 3) * 8)) & 255;
          const float qq    = ((t&3)==0) ? q.x : ((t&3)==1) ? q.y : ((t&3)==2) ? q.z : q.w;
          const float wgt   = qq * zz;
          const _Float16 h  = (_Float16)wgt;
          *(_Float16*)swzp(Whp, (cell<<6) + (ep<<1)) = h;
          *(_Float16*)swzp(Wlp, (cell<<6) + (ep<<1)) = (_Float16)(wgt - (float)h);
        }
      }
    }
    __syncthreads();                       // both tiles staged
    {
      const half8_t ah = *(const half8_t*)swzp(Wh0, ((wv*16 + frow)<<6) + fb);
      const half8_t al = *(const half8_t*)swzp(Wl0, ((wv*16 + frow)<<6) + fb);
      #pragma unroll
      for(int nt=0; nt<4; ++nt){
        const half8_t bh = *(const half8_t*)swzp(Fh0, ((nt*16 + frow)<<6) + fb);
        const half8_t bl = *(const half8_t*)swzp(Fl0, ((nt*16 + frow)<<6) + fb);
        acc[nt] = __builtin_amdgcn_mfma_f32_16x16x32_f16(ah, bh, acc[nt], 0, 0, 0);
        acc[nt] = __builtin_amdgcn_mfma_f32_16x16x32_f16(al, bh, acc[nt], 0, 0, 0);
        acc[nt] = __builtin_amdgcn_mfma_f32_16x16x32_f16(ah, bl, acc[nt], 0, 0, 0);
      }
    }
    {
      const half8_t ah = *(const half8_t*)swzp(Wh1, ((wv*16 + frow)<<6) + fb);
      const half8_t al = *(const half8_t*)swzp(Wl1, ((wv*16 + frow)<<6) + fb);
      #pragma unroll
      for(int nt=0; nt<4; ++nt){
        const half8_t bh = *(const half8_t*)swzp(Fh1, ((nt*16 + frow)<<6) + fb);
        const half8_t bl = *(const half8_t*)swzp(Fl1, ((nt*16 + frow)<<6) + fb);
        acc[nt] = __builtin_amdgcn_mfma_f32_16x16x32_f16(ah, bh, acc[nt], 0, 0, 0);
        acc[nt] = __builtin_amdgcn_mfma_f32_16x16x32_f16(al, bh, acc[nt], 0, 0, 0);
        acc[nt] = __builtin_amdgcn_mfma_f32_16x16x32_f16(ah, bl, acc[nt], 0, 0, 0);
      }
    }
  }

  if(!OUT3){
    unsigned* Bg = B + (size_t)blockIdx.x*4160;
    #pragma unroll
    for(int nt=0;nt<4;++nt)
      #pragma unroll
      for(int r=0;r<4;++r){
        const int cell = wv*16 + (lane>>4)*4 + r;
        Bg[cell*64 + nt*16 + (lane&15)] = packf(acc[nt][r]);
      }
    if(tid < 64) Bg[4096 + tid] = Fp[(size_t)node*64 + tid];
  } else {
    float s0=0.f, s1=0.f, s2=0.f;
    #pragma unroll
    for(int nt=0;nt<4;++nt){
      #pragma unroll
      for(int r=0;r<4;++r){
        const int cell = wv*16 + (lane>>4)*4 + r;
        const int j3   = (cell*64 + nt*16 + (lane&15)) * 3;
        const float v  = acc[nt][r];
        s0 = fmaf(v, W3[j3+0], s0);
        s1 = fmaf(v, W3[j3+1], s1);
        s2 = fmaf(v, W3[j3+2], s2);
      }
    }
    #pragma unroll
    for(int off = 32; off > 0; off >>= 1){
      s0 += __shfl_down(s0, off);
      s1 += __shfl_down(s1, off);
      s2 += __shfl_down(s2, off);
    }
    if(lane == 0){
      red[wv*4+0] = s0; red[wv*4+1] = s1; red[wv*4+2] = s2;
    }
    __syncthreads();
    if(tid == 0 && node < NREAL){
      out[node*3+0] += (red[0]+red[4]+red[8] +red[12])*(1.f/128.f);
      out[node*3+1] += (red[1]+red[5]+red[9] +red[13])*(1.f/128.f);
      out[node*3+2] += (red[2]+red[6]+red[10]+red[14])*(1.f/128.f);
    }
  }
}

// ------- MFMA scatter CIN=96 (v2): 64-EDGE PHASES via dual 32-tiles (r17 scat64m port).
// LDS: 16KB Wt + 24KB Ft + 2KB staging = 42KB -> 3 blk/CU = 12 waves (== measured 12.5
// effective of the 7-block single-tile form) -> phase halving should dominate.
// Accumulation order unchanged (round 0 = edges eb..eb+31, round 1 = eb+32..eb+63).
__global__ __launch_bounds__(256) void k_scat96m(
    const unsigned* __restrict__ Fp, const float4* __restrict__ gw,
    const int4* __restrict__ gmz, const int* __restrict__ row_start,
    unsigned* __restrict__ B, int node_base)
{
  __shared__ __align__(128) _Float16 Wh0[64*32];
  __shared__ __align__(128) _Float16 Wl0[64*32];
  __shared__ __align__(128) _Float16 Wh1[64*32];
  __shared__ __align__(128) _Float16 Wl1[64*32];
  __shared__ __align__(128) _Float16 Fh0[96*32];
  __shared__ __align__(128) _Float16 Fl0[96*32];
  __shared__ __align__(128) _Float16 Fh1[96*32];
  __shared__ __align__(128) _Float16 Fl1[96*32];
  __shared__ __align__(16) float4 Sq[64];
  __shared__ __align__(16) int4   Smd[64];

  const int tid  = threadIdx.x;
  const int node = node_base + blockIdx.x;
  const int wv   = tid >> 6;
  const int lane = tid & 63;
  const int frow = lane & 15;
  const int fb   = (lane >> 4) << 4;

  floatx4 acc[6];
  #pragma unroll
  for(int nt=0;nt<6;++nt){ acc[nt][0]=0.f; acc[nt][1]=0.f; acc[nt][2]=0.f; acc[nt][3]=0.f; }

  half8_t hz;
  #pragma unroll
  for(int q8=0;q8<8;++q8) hz[q8] = (_Float16)0;

  const int e0 = row_start[node], e1 = row_start[node+1];

  for(int eb = e0; eb < e1; eb += 64){
    const int n = (e1 - eb < 64) ? (e1 - eb) : 64;
    __syncthreads();
    if(wv == 0){
      int ei = eb + lane; if(ei >= e1) ei = e1 - 1;
      Sq[lane]  = gw[ei];
      Smd[lane] = gmz[ei];
    } else {
      for(int j = tid - 64; j < 1024; j += 192){
        if(j < 256)       ((half8_t*)Wh0)[j]       = hz;
        else if(j < 512)  ((half8_t*)Wl0)[j - 256] = hz;
        else if(j < 768)  ((half8_t*)Wh1)[j - 512] = hz;
        else              ((half8_t*)Wl1)[j - 768] = hz;
      }
    }
    __syncthreads();
    {
      half8_t h0a, l0a, h0b, l0b, h1a, l1a, h1b, l1b;
      #pragma unroll
      for(int j=0;j<8;++j){
        const int d0 = Smd[wv*8 + j].w;
        const unsigned u0 = Fp[(size_t)d0*96 + lane];
        h0a[j] = lo16(u0);
        l0a[j] = hi16(u0);
        const int d1 = Smd[32 + wv*8 + j].w;
        const unsigned u1 = Fp[(size_t)d1*96 + lane];
        h1a[j] = lo16(u1);
        l1a[j] = hi16(u1);
        if(lane < 32){
          const unsigned v0 = Fp[(size_t)d0*96 + 64 + lane];
          h0b[j] = lo16(v0);
          l0b[j] = hi16(v0);
          const unsigned v1 = Fp[(size_t)d1*96 + 64 + lane];
          h1b[j] = lo16(v1);
          l1b[j] = hi16(v1);
        }
      }
      *(half8_t*)swzp(Fh0, (lane<<6) + (wv<<4)) = h0a;
      *(half8_t*)swzp(Fl0, (lane<<6) + (wv<<4)) = l0a;
      *(half8_t*)swzp(Fh1, (lane<<6) + (wv<<4)) = h1a;
      *(half8_t*)swzp(Fl1, (lane<<6) + (wv<<4)) = l1a;
      if(lane < 32){
        *(half8_t*)swzp(Fh0, ((64+lane)<<6) + (wv<<4)) = h0b;
        *(half8_t*)swzp(Fl0, ((64+lane)<<6) + (wv<<4)) = l0b;
        *(half8_t*)swzp(Fh1, ((64+lane)<<6) + (wv<<4)) = h1b;
        *(half8_t*)swzp(Fl1, ((64+lane)<<6) + (wv<<4)) = l1b;
      }
    }
    if(lane < 16){
      const int ei = wv*16 + lane;
      if(ei < n){
        const float4 q  = Sq[ei];
        const int4   md = Smd[ei];
        const float zA = __int_as_float(md.x), zB = 1.f - zA;
        _Float16* Whp = (ei < 32) ? Wh0 : Wh1;
        _Float16* Wlp = (ei < 32) ? Wl0 : Wl1;
        const int ep = ei & 31;
        #pragma unroll
        for(int t=0;t<8;++t){
          const int   cells = (t < 4) ? md.y : md.z;
          const float zz    = (t < 4) ? zA : zB;
          const int   cell  = (cells >> ((t & 3) * 8)) & 255;
          const float qq    = ((t&3)==0) ? q.x : ((t&3)==1) ? q.y : ((t&3)==2) ? q.z : q.w;
          const float wgt   = qq * zz;
          const _Float16 h  = (_Float16)wgt;
          *(_Float16*)swzp(Whp, (cell<<6) + (ep<<1)) = h;
          *(_Float16*)swzp(Wlp, (cell<<6) + (ep<<1)) = (_Float16)(wgt - (float)h);
        }
      }
    }
    __syncthreads();
    {
      const half8_t ah = *(const half8_t*)swzp(Wh0, ((wv*16 + frow)<<6) + fb);
      const half8_t al = *(const half8_t*)swzp(Wl0, ((wv*16 + frow)<<6) + fb);
      #pragma unroll
      for(int nt=0; nt<6; ++nt){
        const half8_t bh = *(const half8_t*)swzp(Fh0, ((nt*16 + frow)<<6) + fb);
        const half8_t bl = *(const half8_t*)swzp(Fl0, ((nt*16 + frow)<<6) + fb);
        acc[nt] = __builtin_amdgcn_mfma_f32_16x16x32_f16(ah, bh, acc[nt], 0, 0, 0);
        acc[nt] = __builtin_amdgcn_mfma_f32_16x16x32_f16(al, bh, acc[nt], 0, 0, 0);
        acc[nt] = __builtin_amdgcn_mfma_f32_16x16x32_f16(ah, bl, acc[nt], 0, 0, 0);
      }
    }
    {
      const half8_t ah = *(const half8_t*)swzp(Wh1, ((wv*16 + frow)<<6) + fb);
      const half8_t al = *(const half8_t*)swzp(Wl1, ((wv*16 + frow)<<6) + fb);
      #pragma unroll
      for(int nt=0; nt<6; ++nt){
        const half8_t bh = *(const half8_t*)swzp(Fh1, ((nt*16 + frow)<<6) + fb);
        const half8_t bl = *(const half8_t*)swzp(Fl1, ((nt*16 + frow)<<6) + fb);
        acc[nt] = __builtin_amdgcn_mfma_f32_16x16x32_f16(ah, bh, acc[nt], 0, 0, 0);
        acc[nt] = __builtin_amdgcn_mfma_f32_16x16x32_f16(al, bh, acc[nt], 0, 0, 0);
        acc[nt] = __builtin_amdgcn_mfma_f32_16x16x32_f16(ah, bl, acc[nt], 0, 0, 0);
      }
    }
  }

  unsigned* Bg = B + (size_t)blockIdx.x*6240;
  #pragma unroll
  for(int nt=0;nt<6;++nt)
    #pragma unroll
    for(int r=0;r<4;++r){
      const int cell = wv*16 + (lane>>4)*4 + r;
      Bg[cell*96 + nt*16 + (lane&15)] = packf(acc[nt][r]);
    }
  if(tid < 96) Bg[6144 + tid] = Fp[(size_t)node*96 + tid];
}

// ------- scatter CIN=13 (RMW form), packed-B epilogue -------------------------------------
__global__ __launch_bounds__(128) void k_scat13(
    const float* __restrict__ feat, const float4* __restrict__ gw,
    const int4* __restrict__ gmz, const int* __restrict__ row_start,
    unsigned* __restrict__ B, int node_base)
{
  constexpr int CIN = 13, BSZ = KK*CIN, ESW = 4, CSTRIDE = BSZ + 8;
  __shared__ __align__(16) float Bl[ESW*CSTRIDE];
  const int tid  = threadIdx.x;
  const int node = node_base + blockIdx.x;

  for(int j = tid; j < ESW*CSTRIDE; j += 128) Bl[j] = 0.f;

  const int e0 = row_start[node], e1 = row_start[node+1];
  const int wv   = tid >> 6;
  const int lane = tid & 63;
  const int slot = lane >> 4;
  const int c    = lane & 15;
  const bool act = (c < CIN);
  float* Bp = Bl + slot*CSTRIDE;
  __syncthreads();

  if(act){
    for(int e = e0 + slot; e < e1; e += ESW){
      const float4 q  = gw[e];
      const int4   md = gmz[e];
      const float zA = __int_as_float(md.x);
      const float z  = wv ? (1.f - zA) : zA;
      const int   cp = wv ? md.z : md.y;
      float v = feat[(size_t)md.w*CIN + c] * z;
      const int b0 = ( cp        & 255)*CIN + c;
      const int b1 = ((cp >> 8)  & 255)*CIN + c;
      const int b2 = ((cp >> 16) & 255)*CIN + c;
      const int b3 = (((unsigned)cp) >> 24)*CIN + c;
      float o0 = Bp[b0], o1 = Bp[b1], o2 = Bp[b2], o3 = Bp[b3];
      o0 = fmaf(q.x, v, o0); o1 = fmaf(q.y, v, o1);
      o2 = fmaf(q.z, v, o2); o3 = fmaf(q.w, v, o3);
      Bp[b0] = o0; Bp[b1] = o1; Bp[b2] = o2; Bp[b3] = o3;
    }
  }
  __syncthreads();

  unsigned* Bg = B + (size_t)blockIdx.x*BSZ;
  for(int j = tid*4; j < BSZ; j += 512){
    float4 a = *(const float4*)&Bl[j];
    #pragma unroll
    for(int k = 1; k < ESW; ++k){
      const float4 t = *(const float4*)&Bl[k*CSTRIDE + j];
      a.x += t.x; a.y += t.y; a.z += t.z; a.w += t.w;
    }
    uint4 o;
    o.x = packf(a.x); o.y = packf(a.y); o.z = packf(a.z); o.w = packf(a.w);
    *(uint4*)&Bg[j] = o;
  }
}

// ---- W pre-pass: transpose + split fp32 -> f16 hi/lo. WhT/WlT layout [64 cols][Ktot k];
// conv weights at k=0..Kcnv-1.
__global__ void k_cvtW(const float* __restrict__ W, _Float16* __restrict__ WhT,
                       _Float16* __restrict__ WlT, int Kcnv, int Ktot)
{
  int idx = blockIdx.x*blockDim.x + threadIdx.x;
  if(idx >= 64*Kcnv) return;
  int o = idx / Kcnv, k = idx - o*Kcnv;
  float w = W[(size_t)k*64 + o];
  _Float16 h = (_Float16)w;
  WhT[(size_t)o*Ktot + k] = h;
  WlT[(size_t)o*Ktot + k] = (_Float16)(w - (float)h);
}

// ---- dense-weight append: dW[cin][64] -> WhT/WlT rows k = koff..koff+Kcin-1 (fusion).
__global__ void k_cvtWd(const float* __restrict__ dW, _Float16* __restrict__ WhT,
                        _Float16* __restrict__ WlT, int Kcin, int Ktot, int koff)
{
  int idx = blockIdx.x*blockDim.x + threadIdx.x;
  if(idx >= 64*Kcin) return;
  int o = idx / Kcin, c = idx - o*Kcin;
  float w = dW[(size_t)c*64 + o];
  _Float16 h = (_Float16)w;
  WhT[(size_t)o*Ktot + koff + c] = h;
  WlT[(size_t)o*Ktot + koff + c] = (_Float16)(w - (float)h);
}

// ---- MFMA GEMM: M=64 tile, packed pre-split A. Kd = TOTAL K (conv cells + fused dense).
__global__ __launch_bounds__(256) void k_gemm_mfma(
    const unsigned* __restrict__ Ap, const _Float16* __restrict__ WhT,
    const _Float16* __restrict__ WlT, float* __restrict__ P,
    int M, int Kd, int node_base, int ksteps_per)
{
  __shared__ __align__(128) _Float16 Ah[64*32];
  __shared__ __align__(128) _Float16 Al[64*32];
  __shared__ __align__(128) _Float16 Bh[64*32];
  __shared__ __align__(128) _Float16 Blo[64*32];
  const int tid = threadIdx.x;
  const int mbase = blockIdx.x * 64;
  const int s = blockIdx.y;
  const int kt0 = s * ksteps_per * 32;
  const int kt1 = min(Kd, kt0 + ksteps_per*32);
  const int wv = tid >> 6, lane = tid & 63;
  const int row  = tid >> 2;          // staging row (A row / W col), 0..63
  const int useg = (tid & 3) * 8;     // u32 seg (8 u32 per thread) within 32-wide tile
  const int sb   = (tid & 3) << 4;    // staging byte col (16B per thread per buf)
  const int frow = lane & 15;
  const int fb   = (lane >> 4) << 4;  // frag byte col

  floatx4 acc[4];
  #pragma unroll
  for(int c=0;c<4;++c){ acc[c][0]=0.f; acc[c][1]=0.f; acc[c][2]=0.f; acc[c][3]=0.f; }

  const int grow = mbase + row;
  const unsigned* Arow = (grow < M) ? (Ap + (size_t)grow*Kd) : nullptr;
  const _Float16* WhRow = WhT + (size_t)row*Kd;
  const _Float16* WlRow = WlT + (size_t)row*Kd;

  for(int kt = kt0; kt < kt1; kt += 32){
    unsigned au[8];
    if(Arow){
      *(uint4*)&au[0] = *(const uint4*)(Arow + kt + useg);
      *(uint4*)&au[4] = *(const uint4*)(Arow + kt + useg + 4);
    } else {
      #pragma unroll
      for(int j=0;j<8;++j) au[j] = 0u;
    }
    half8_t hv, lv;
    #pragma unroll
    for(int j=0;j<8;++j){
      hv[j] = lo16(au[j]);
      lv[j] = hi16(au[j]);
    }
    half8_t wh = *(const half8_t*)(WhRow + kt + useg);
    half8_t wl = *(const half8_t*)(WlRow + kt + useg);
    __syncthreads();                        // previous iter's frag reads complete
    *(half8_t*)swzp(Ah,  (row<<6) + sb) = hv;
    *(half8_t*)swzp(Al,  (row<<6) + sb) = lv;
    *(half8_t*)swzp(Bh,  (row<<6) + sb) = wh;
    *(half8_t*)swzp(Blo, (row<<6) + sb) = wl;
    __syncthreads();                        // staged tile visible
    const half8_t ah = *(const half8_t*)swzp(Ah, ((wv*16 + frow)<<6) + fb);
    const half8_t al = *(const half8_t*)swzp(Al, ((wv*16 + frow)<<6) + fb);
    #pragma unroll
    for(int c=0;c<4;++c){
      const half8_t bh = *(const half8_t*)swzp(Bh,  ((c*16 + frow)<<6) + fb);
      const half8_t bl = *(const half8_t*)swzp(Blo, ((c*16 + frow)<<6) + fb);
      acc[c] = __builtin_amdgcn_mfma_f32_16x16x32_f16(ah, bh, acc[c], 0, 0, 0);
      acc[c] = __builtin_amdgcn_mfma_f32_16x16x32_f16(al, bh, acc[c], 0, 0, 0);
      acc[c] = __builtin_amdgcn_mfma_f32_16x16x32_f16(ah, bl, acc[c], 0, 0, 0);
    }
  }

  const int prow0 = mbase + wv*16 + (lane>>4)*4;
  const int pcol  = lane & 15;
  #pragma unroll
  for(int c=0;c<4;++c){
    #pragma unroll
    for(int r=0;r<4;++r){
      const int rr = prow0 + r;
      if(rr < M)
        P[((size_t)s*NPTS + node_base + rr)*64 + c*16 + pcol] = acc[c][r];
    }
  }
}

// ---- combine partials: x[node*ldout+colofs+o] += sum_s P[s][node][o]
template<int S>
__global__ void k_combine(const float* __restrict__ P, float* __restrict__ x,
                          int ldout, int colofs)
{
  int idx = blockIdx.x*blockDim.x + threadIdx.x;
  if(idx >= NPTS*16) return;
  int node = idx >> 4, c4 = (idx & 15) * 4;
  float4 s = *(const float4*)(P + (size_t)node*64 + c4);
  #pragma unroll
  for(int k=1;k<S;++k){
    float4 t = *(const float4*)(P + ((size_t)k*NPTS + node)*64 + c4);
    s.x+=t.x; s.y+=t.y; s.z+=t.z; s.w+=t.w;
  }
  float* xp = x + (size_t)node*ldout + colofs + c4;
  float4 o = *(float4*)xp;
  o.x+=s.x; o.y+=s.y; o.z+=s.z; o.w+=s.w;
  *(float4*)xp = o;
}

// ---------------- dense/bias paths ----------------
__global__ void k_dense0(const float* __restrict__ f, const float* __restrict__ dW,
                         const float* __restrict__ db, const float* __restrict__ cb0,
                         float* __restrict__ out)
{
  int idx = blockIdx.x*blockDim.x + threadIdx.x;
  if(idx >= NPTS*96) return;
  int i = idx/96, c = idx - i*96;
  if(c < 64){ out[idx] = cb0[c]; return; }
  int o = c - 64;
  float s = db[o];
  const float* row = f + (size_t)i*13;
  #pragma unroll
  for(int j=0;j<13;++j) s = fmaf(row[j], dW[j*32+o], s);
  out[idx] = s;
}

// bias init (dense matvec now fused into the GEMM K): x = db + cb (+ resid)
__global__ void k_bias(const float* __restrict__ db, const float* __restrict__ cb,
                       const float* __restrict__ resid, float* __restrict__ out)
{
  int idx = blockIdx.x*blockDim.x + threadIdx.x;
  if(idx >= NPTS*64) return;
  int o = idx & 63;
  float s = db[o] + cb[o];
  if(resid) s += resid[idx];
  out[idx] = s;
}

__global__ void k_dense3(const float* __restrict__ x2, const float* __restrict__ dW,
                         const float* __restrict__ db, const float* __restrict__ cb,
                         float* __restrict__ out)
{
  int idx = blockIdx.x*blockDim.x + threadIdx.x;
  if(idx >= NREAL*3) return;
  int i = idx/3, o = idx - i*3;
  float s = db[o] + cb[o];
  const float* row = x2 + (size_t)i*64;
  for(int c=0;c<64;++c) s = fmaf(fmaxf(row[c],0.f), dW[c*3+o], s);
  out[idx] = s * (1.f/128.f);
}

// ---------------- host ----------------
static inline size_t alup(size_t x){ return (x + 255) & ~(size_t)255; }

static inline int calc_rows(size_t bcap, int u32row, int want){
  size_t perrow = (size_t)u32row * 4;
  size_t r = (perrow > 0) ? bcap / perrow : 0;
  if(r >= (size_t)want) return want;
  r = (r / 128) * 128;
  if(r < 128) r = 128;
  return (int)r;
}

extern "C" void kernel_launch(void* const* d_in, const int* in_sizes, int n_in,
                              void* d_out, int out_size, void* d_ws, size_t ws_size,
                              hipStream_t stream)
{
  const float* pos   = (const float*)d_in[0];
  const float* feats = (const float*)d_in[1];
  const int*   esrc  = (const int*)d_in[2];
  const int*   edst  = (const int*)d_in[3];
  const float* c0w = (const float*)d_in[4];
  const float* c0b = (const float*)d_in[5];
  const float* d0w = (const float*)d_in[6];
  const float* d0b = (const float*)d_in[7];
  const float* c1w = (const float*)d_in[8];
  const float* c1b = (const float*)d_in[9];
  const float* d1w = (const float*)d_in[10];
  const float* d1b = (const float*)d_in[11];
  const float* c2w = (const float*)d_in[12];
  const float* c2b = (const float*)d_in[13];
  const float* d2w = (const float*)d_in[14];
  const float* d2b = (const float*)d_in[15];
  const float* c3w = (const float*)d_in[16];
  const float* c3b = (const float*)d_in[17];
  const float* d3w = (const float*)d_in[18];
  const float* d3b = (const float*)d_in[19];
  float* out = (float*)d_out;

  char* w = (char*)d_ws;
  size_t off = 0;
  float* f  = (float*)(w+off); off += alup((size_t)NPTS*13*4);
  float* x0 = (float*)(w+off); off += alup((size_t)NPTS*96*4);
  float* x1 = (float*)(w+off); off += alup((size_t)NPTS*64*4);
  float* x2 = (float*)(w+off); off += alup((size_t)NPTS*64*4);
  int* row_start = (int*)(w+off); off += alup((size_t)(NPTS+1)*4);
  int* ereal = (int*)(w+off);     off += alup(16);
  float4* gw = (float4*)(w+off);  off += alup((size_t)EPAD*16);     // per-edge xy weights
  int4*  gmz = (int4*)(w+off);    off += alup((size_t)EPAD*16);     // per-edge zA+cells+dst
  float* P  = (float*)(w+off); off += alup((size_t)8*NPTS*64*4);    // split-K partials
  _Float16* whT = (_Float16*)(w+off); off += alup((size_t)64*6400*2); // W hi (transposed, Ktot<=6240)
  _Float16* wlT = (_Float16*)(w+off); off += alup((size_t)64*6400*2); // W lo (transposed)
  unsigned* Fp0 = (unsigned*)(w+off); off += alup((size_t)NPTS*96*4); // packed pre-split feats (96ch)
  unsigned* Fp1 = (unsigned*)(w+off); off += alup((size_t)NPTS*64*4); // packed pre-split feats (64ch)
  unsigned* B = (unsigned*)(w+off);                                   // packed pre-split B
  size_t bcap = (ws_size > off) ? (ws_size - off) : 0;

  k_find_ereal<<<1,1,0,stream>>>(edst, ereal);
  k_csr<<<(NPTS+1+255)/256,256,0,stream>>>(esrc, ereal, row_start);
  k_build_f<<<(NPTS*13+255)/256,256,0,stream>>>(feats, f);
  k_geom<<<(EPAD+255)/256,256,0,stream>>>(pos, esrc, edst, gw, gmz);

  // ---- layer 0: x0[:,0:64] = cconv0(f)+c0b ; x0[:,64:96] = f@d0w+d0b  (chunk 8192)
  k_dense0<<<(NPTS*96+255)/256,256,0,stream>>>(f, d0w, d0b, c0b, x0);
  {
    k_cvtW<<<(64*832+255)/256,256,0,stream>>>(c0w, whT, wlT, 832, 832);
    int rows = calc_rows(bcap, 832, 8192);
    for(int base = 0; base < NPTS; base += rows){
      int m = (NPTS - base < rows) ? (NPTS - base) : rows;
      k_scat13<<<m,128,0,stream>>>(f, gw, gmz, row_start, B, base);
      k_gemm_mfma<<<dim3((m+63)/64, 8),256,0,stream>>>(B, whT, wlT, P, m, 832, base, 4);
    }
    k_combine<8><<<(NPTS*16+255)/256,256,0,stream>>>(P, x0, 96, 0);
  }

  // ---- layer 1: x1 = cconv1(relu(x0)) + relu(x0)@d1w + d1b + c1b
  //      dense fused into GEMM: Kd = 6144 + 96
  k_bias<<<(NPTS*64+255)/256,256,0,stream>>>(d1b, c1b, nullptr, x1);
  {
    k_cvtW<<<(64*6144+255)/256,256,0,stream>>>(c1w, whT, wlT, 6144, 6240);
    k_cvtWd<<<(64*96+255)/256,256,0,stream>>>(d1w, whT, wlT, 96, 6240, 6144);
    k_cvtF<<<(NPTS*96+255)/256,256,0,stream>>>(x0, Fp0, NPTS*96);
    int rows = calc_rows(bcap, 6240, 4096);
    for(int base = 0; base < NPTS; base += rows){
      int m = (NPTS - base < rows) ? (NPTS - base) : rows;
      k_scat96m<<<m,256,0,stream>>>(Fp0, gw, gmz, row_start, B, base);
      k_gemm_mfma<<<dim3((m+63)/64, 8),256,0,stream>>>(B, whT, wlT, P, m, 6240, base, 25);
    }
    k_combine<8><<<(NPTS*16+255)/256,256,0,stream>>>(P, x1, 64, 0);
  }

  // ---- layer 2: x2 = cconv2(relu(x1)) + relu(x1)@d2w + d2b + c2b + x1
  //      dense fused into GEMM: Kd = 4096 + 64
  k_bias<<<(NPTS*64+255)/256,256,0,stream>>>(d2b, c2b, x1, x2);
  {
    k_cvtW<<<(64*4096+255)/256,256,0,stream>>>(c2w, whT, wlT, 4096, 4160);
    k_cvtWd<<<(64*64+255)/256,256,0,stream>>>(d2w, whT, wlT, 64, 4160, 4096);
    k_cvtF<<<(NPTS*64+255)/256,256,0,stream>>>(x1, Fp1, NPTS*64);
    int rows = calc_rows(bcap, 4160, 4096);
    for(int base = 0; base < NPTS; base += rows){
      int m = (NPTS - base < rows) ? (NPTS - base) : rows;
      k_scat64m<0><<<m,256,0,stream>>>(Fp1, gw, gmz, row_start, B, base, nullptr, nullptr);
      k_gemm_mfma<<<dim3((m+63)/64, 8),256,0,stream>>>(B, whT, wlT, P, m, 4160, base, 17);
    }
    k_combine<8><<<(NPTS*16+255)/256,256,0,stream>>>(P, x2, 64, 0);
  }

  // ---- layer 3 (fused): out = dense3 part, then scatter adds conv3 GEMV directly
  k_dense3<<<(NREAL*3+255)/256,256,0,stream>>>(x2, d3w, d3b, c3b, out);
  k_cvtF<<<(NPTS*64+255)/256,256,0,stream>>>(x2, Fp1, NPTS*64);
  k_scat64m<1><<<NPTS,256,0,stream>>>(Fp1, gw, gmz, row_start, nullptr, 0, c3w, out);
}

// Round 19
// 881.297 us; speedup vs baseline: 1.0109x; 1.0109x over previous
//
#include <hip/hip_runtime.h>
#include <math.h>

#define NPTS   20001
#define NREAL  20000
#define EPAD   1200000
#define KK     64
#define RADF   0.1125f

typedef _Float16 half8_t __attribute__((ext_vector_type(8)));
typedef float    floatx4 __attribute__((ext_vector_type(4)));

__device__ __forceinline__ float sgnf(float v){ return v>0.f ? 1.f : (v<0.f ? -1.f : 0.f); }
__device__ __forceinline__ _Float16 lo16(unsigned u){ return __builtin_bit_cast(_Float16, (unsigned short)(u & 0xffffu)); }
__device__ __forceinline__ _Float16 hi16(unsigned u){ return __builtin_bit_cast(_Float16, (unsigned short)(u >> 16)); }
// deterministic fp32 -> packed f16 hi/lo split (hi in low 16 bits).
__device__ __forceinline__ unsigned packf(float v){
  _Float16 h = (_Float16)v;
  _Float16 l = (_Float16)(v - (float)h);
  return (unsigned)__builtin_bit_cast(unsigned short, h)
       | ((unsigned)__builtin_bit_cast(unsigned short, l) << 16);
}

// byte-offset XOR swizzle for [rows][32]-half (64B-row) LDS tiles.
__device__ __forceinline__ void* swzp(void* base, int byteoff){
  return (void*)((char*)base + (byteoff ^ (((byteoff >> 6) & 7) << 4)));
}
__device__ __forceinline__ const void* swzp(const void* base, int byteoff){
  return (const void*)((const char*)base + (byteoff ^ (((byteoff >> 6) & 7) << 4)));
}

// ---------------- CSR build (edge_src is sorted; pad edges have dst==NREAL) ----------------
__global__ void k_find_ereal(const int* __restrict__ dst, int* __restrict__ ereal){
  int lo=0, hi=EPAD;
  while(lo<hi){ int mid=(lo+hi)>>1; if(dst[mid]==NREAL) hi=mid; else lo=mid+1; }
  *ereal = lo;
}

__global__ void k_csr(const int* __restrict__ src, const int* __restrict__ erealp,
                      int* __restrict__ row_start){
  int i = blockIdx.x*blockDim.x + threadIdx.x;
  if(i > NPTS) return;
  int E = *erealp;
  int lo=0, hi=E;
  while(lo<hi){ int mid=(lo+hi)>>1; if(src[mid] < i) lo=mid+1; else hi=mid; }
  row_start[i] = lo;
}

__global__ void k_build_f(const float* __restrict__ feats, float* __restrict__ f){
  int idx = blockIdx.x*blockDim.x + threadIdx.x;
  if(idx >= NPTS*13) return;
  int i = idx/13, c = idx - i*13;
  f[idx] = (c==0) ? 1.f : feats[i*12 + (c-1)];
}

// ---- feature pre-pass: relu + split + pack, once per layer.
__global__ void k_cvtF(const float* __restrict__ x, unsigned* __restrict__ Fp, int total){
  int idx = blockIdx.x*blockDim.x + threadIdx.x;
  if(idx >= total) return;
  Fp[idx] = packf(fmaxf(x[idx], 0.f));
}

// ---------------- per-edge geometry (exact port of ball_to_cube + window) ----------------
__device__ __forceinline__ void edge_geom(float ox, float oy, float oz,
                                          float& win, float& t0, float& t1, float& t2, int& f0p){
  const float eps = 1e-9f;
  float sq = ox*ox + oy*oy + oz*oz;
  float u = 1.f - sq;
  win = fminf(fmaxf(u*u*u, 0.f), 1.f);
  float norm = sqrtf(sq + eps);
  float rxy2 = ox*ox + oy*oy;
  bool polar = (1.25f*oz*oz > rxy2);
  float s_p = sqrtf(3.f*norm/(norm + fabsf(oz) + eps));
  float s_n = norm / sqrtf(rxy2 + eps);
  float s = polar ? s_p : s_n;
  float xc = ox*s, yc = oy*s;
  float zc = polar ? sgnf(oz)*norm : 1.5f*oz;
  if(sq < 1e-12f){ xc = 0.f; yc = 0.f; zc = 0.f; }
  float r = sqrtf(xc*xc + yc*yc + eps);
  bool c1 = fabsf(xc) >= fabsf(yc);
  float xs = (fabsf(xc) < eps) ? eps : xc;
  float ys = (fabsf(yc) < eps) ? eps : yc;
  const float fop = 1.2732395447351628f; // float32(4/pi)
  float a = c1 ? sgnf(xc)*r : sgnf(yc)*r*fop*atanf(xc/ys);
  float b = c1 ? sgnf(xc)*r*fop*atanf(yc/xs) : sgnf(yc)*r;
  if(xc*xc + yc*yc < 1e-12f){ a = 0.f; b = 0.f; }
  float g0 = fminf(fmaxf((a *0.5f+0.5f)*3.f, 0.f), 3.f);
  float g1 = fminf(fmaxf((b *0.5f+0.5f)*3.f, 0.f), 3.f);
  float g2 = fminf(fmaxf((zc*0.5f+0.5f)*3.f, 0.f), 3.f);
  float f00 = floorf(g0), f01 = floorf(g1), f02 = floorf(g2);
  t0 = g0 - f00; t1 = g1 - f01; t2 = g2 - f02;
  f0p = (int)f00 | ((int)f01 << 2) | ((int)f02 << 4);
}

// ---- k_geom: per-edge staged data, computed ONCE (shared by all 4 scatter layers).
__global__ __launch_bounds__(256) void k_geom(const float* __restrict__ pos,
    const int* __restrict__ esrc, const int* __restrict__ edst,
    float4* __restrict__ gw, int4* __restrict__ gmz)
{
  int e = blockIdx.x*blockDim.x + threadIdx.x;
  if(e >= EPAD) return;
  const int sn = esrc[e], d = edst[e];
  const float ox = (pos[d*3+0]-pos[sn*3+0])/RADF;
  const float oy = (pos[d*3+1]-pos[sn*3+1])/RADF;
  const float oz = (pos[d*3+2]-pos[sn*3+2])/RADF;
  float win, t0, t1, t2; int f0p;
  edge_geom(ox, oy, oz, win, t0, t1, t2, f0p);
  const int i0 = f0p & 3, i1 = (f0p>>2) & 3, i2 = f0p >> 4;
  const int X0 = i0 << 4, X1 = ((i0+1)&3) << 4;
  const int Y0 = i1 << 2, Y1 = ((i1+1)&3) << 2;
  const int Z0 = i2, Z1 = (i2+1) & 3;
  const float wx0 = win*(1.f-t0), wx1 = win*t0;
  const float wy0 = 1.f-t1, wy1 = t1;
  const float wz0 = 1.f-t2, wz1 = t2;
  gw[e] = make_float4(wx0*wy0, wx0*wy1, wx1*wy0, wx1*wy1);
  const int p0 = Z0 & 1;
  const float zA = p0 ? wz1 : wz0;                  // weight for parity-0 (even z) cell
  const int   cA = p0 ? Z1 : Z0;                    // even-z cell
  const int   cB = p0 ? Z0 : Z1;                    // odd-z cell
  const int cells0 = (X0|Y0|cA) | ((X0|Y1|cA)<<8) | ((X1|Y0|cA)<<16) | ((X1|Y1|cA)<<24);
  const int cells1 = (X0|Y0|cB) | ((X0|Y1|cB)<<8) | ((X1|Y0|cB)<<16) | ((X1|Y1|cB)<<24);
  gmz[e] = make_int4(__float_as_int(zA), cells0, cells1, d);
}

// ------- MFMA scatter CIN=64 (v7): 64-EDGE PHASES via dual 32-tiles (r17/r18: 124->111us).
template<int OUT3>
__global__ __launch_bounds__(256) void k_scat64m(
    const unsigned* __restrict__ Fp, const float4* __restrict__ gw,
    const int4* __restrict__ gmz, const int* __restrict__ row_start,
    unsigned* __restrict__ B, int node_base,
    const float* __restrict__ W3, float* __restrict__ out)
{
  __shared__ __align__(128) _Float16 Wh0[64*32];
  __shared__ __align__(128) _Float16 Wl0[64*32];
  __shared__ __align__(128) _Float16 Wh1[64*32];
  __shared__ __align__(128) _Float16 Wl1[64*32];
  __shared__ __align__(128) _Float16 Fh0[64*32];
  __shared__ __align__(128) _Float16 Fl0[64*32];
  __shared__ __align__(128) _Float16 Fh1[64*32];
  __shared__ __align__(128) _Float16 Fl1[64*32];
  __shared__ __align__(16) float4 Sq[64];
  __shared__ __align__(16) int4   Smd[64];
  __shared__ float red[16];

  const int tid  = threadIdx.x;
  const int node = node_base + blockIdx.x;
  const int wv   = tid >> 6;
  const int lane = tid & 63;
  const int frow = lane & 15;
  const int fb   = (lane >> 4) << 4;   // frag col byte offset

  floatx4 acc[4];
  #pragma unroll
  for(int nt=0;nt<4;++nt){ acc[nt][0]=0.f; acc[nt][1]=0.f; acc[nt][2]=0.f; acc[nt][3]=0.f; }

  half8_t hz;
  #pragma unroll
  for(int q8=0;q8<8;++q8) hz[q8] = (_Float16)0;

  const int e0 = row_start[node], e1 = row_start[node+1];

  for(int eb = e0; eb < e1; eb += 64){
    const int n = (e1 - eb < 64) ? (e1 - eb) : 64;
    __syncthreads();                       // prior frag + Sq/Smd reads complete
    if(wv == 0){
      int ei = eb + lane; if(ei >= e1) ei = e1 - 1;   // clamp tail (scatter guarded by n)
      Sq[lane]  = gw[ei];
      Smd[lane] = gmz[ei];
    } else {
      for(int j = tid - 64; j < 1024; j += 192){
        if(j < 256)       ((half8_t*)Wh0)[j]       = hz;
        else if(j < 512)  ((half8_t*)Wl0)[j - 256] = hz;
        else if(j < 768)  ((half8_t*)Wh1)[j - 512] = hz;
        else              ((half8_t*)Wl1)[j - 768] = hz;
      }
    }
    __syncthreads();                       // Sq/Smd + zeroed Wt visible
    {
      half8_t h0r, l0r, h1r, l1r;
      #pragma unroll
      for(int j=0;j<8;++j){
        const int d0 = Smd[wv*8 + j].w;
        const unsigned u0 = Fp[(size_t)d0*64 + lane];
        h0r[j] = lo16(u0);
        l0r[j] = hi16(u0);
        const int d1 = Smd[32 + wv*8 + j].w;
        const unsigned u1 = Fp[(size_t)d1*64 + lane];
        h1r[j] = lo16(u1);
        l1r[j] = hi16(u1);
      }
      *(half8_t*)swzp(Fh0, (lane<<6) + (wv<<4)) = h0r;
      *(half8_t*)swzp(Fl0, (lane<<6) + (wv<<4)) = l0r;
      *(half8_t*)swzp(Fh1, (lane<<6) + (wv<<4)) = h1r;
      *(half8_t*)swzp(Fl1, (lane<<6) + (wv<<4)) = l1r;
    }
    if(lane < 16){
      const int ei = wv*16 + lane;         // 4 waves x 16 = 64 edges
      if(ei < n){
        const float4 q  = Sq[ei];
        const int4   md = Smd[ei];
        const float zA = __int_as_float(md.x), zB = 1.f - zA;
        _Float16* Whp = (ei < 32) ? Wh0 : Wh1;
        _Float16* Wlp = (ei < 32) ? Wl0 : Wl1;
        const int ep = ei & 31;
        #pragma unroll
        for(int t=0;t<8;++t){
          const int   cells = (t < 4) ? md.y : md.z;
          const float zz    = (t < 4) ? zA : zB;
          const int   cell  = (cells >> ((t & 3) * 8)) & 255;
          const float qq    = ((t&3)==0) ? q.x : ((t&3)==1) ? q.y : ((t&3)==2) ? q.z : q.w;
          const float wgt   = qq * zz;
          const _Float16 h  = (_Float16)wgt;
          *(_Float16*)swzp(Whp, (cell<<6) + (ep<<1)) = h;
          *(_Float16*)swzp(Wlp, (cell<<6) + (ep<<1)) = (_Float16)(wgt - (float)h);
        }
      }
    }
    __syncthreads();                       // both tiles staged
    {
      const half8_t ah = *(const half8_t*)swzp(Wh0, ((wv*16 + frow)<<6) + fb);
      const half8_t al = *(const half8_t*)swzp(Wl0, ((wv*16 + frow)<<6) + fb);
      #pragma unroll
      for(int nt=0; nt<4; ++nt){
        const half8_t bh = *(const half8_t*)swzp(Fh0, ((nt*16 + frow)<<6) + fb);
        const half8_t bl = *(const half8_t*)swzp(Fl0, ((nt*16 + frow)<<6) + fb);
        acc[nt] = __builtin_amdgcn_mfma_f32_16x16x32_f16(ah, bh, acc[nt], 0, 0, 0);
        acc[nt] = __builtin_amdgcn_mfma_f32_16x16x32_f16(al, bh, acc[nt], 0, 0, 0);
        acc[nt] = __builtin_amdgcn_mfma_f32_16x16x32_f16(ah, bl, acc[nt], 0, 0, 0);
      }
    }
    {
      const half8_t ah = *(const half8_t*)swzp(Wh1, ((wv*16 + frow)<<6) + fb);
      const half8_t al = *(const half8_t*)swzp(Wl1, ((wv*16 + frow)<<6) + fb);
      #pragma unroll
      for(int nt=0; nt<4; ++nt){
        const half8_t bh = *(const half8_t*)swzp(Fh1, ((nt*16 + frow)<<6) + fb);
        const half8_t bl = *(const half8_t*)swzp(Fl1, ((nt*16 + frow)<<6) + fb);
        acc[nt] = __builtin_amdgcn_mfma_f32_16x16x32_f16(ah, bh, acc[nt], 0, 0, 0);
        acc[nt] = __builtin_amdgcn_mfma_f32_16x16x32_f16(al, bh, acc[nt], 0, 0, 0);
        acc[nt] = __builtin_amdgcn_mfma_f32_16x16x32_f16(ah, bl, acc[nt], 0, 0, 0);
      }
    }
  }

  if(!OUT3){
    unsigned* Bg = B + (size_t)blockIdx.x*4160;
    #pragma unroll
    for(int nt=0;nt<4;++nt)
      #pragma unroll
      for(int r=0;r<4;++r){
        const int cell = wv*16 + (lane>>4)*4 + r;
        Bg[cell*64 + nt*16 + (lane&15)] = packf(acc[nt][r]);
      }
    if(tid < 64) Bg[4096 + tid] = Fp[(size_t)node*64 + tid];
  } else {
    float s0=0.f, s1=0.f, s2=0.f;
    #pragma unroll
    for(int nt=0;nt<4;++nt){
      #pragma unroll
      for(int r=0;r<4;++r){
        const int cell = wv*16 + (lane>>4)*4 + r;
        const int j3   = (cell*64 + nt*16 + (lane&15)) * 3;
        const float v  = acc[nt][r];
        s0 = fmaf(v, W3[j3+0], s0);
        s1 = fmaf(v, W3[j3+1], s1);
        s2 = fmaf(v, W3[j3+2], s2);
      }
    }
    #pragma unroll
    for(int off = 32; off > 0; off >>= 1){
      s0 += __shfl_down(s0, off);
      s1 += __shfl_down(s1, off);
      s2 += __shfl_down(s2, off);
    }
    if(lane == 0){
      red[wv*4+0] = s0; red[wv*4+1] = s1; red[wv*4+2] = s2;
    }
    __syncthreads();
    if(tid == 0 && node < NREAL){
      out[node*3+0] += (red[0]+red[4]+red[8] +red[12])*(1.f/128.f);
      out[node*3+1] += (red[1]+red[5]+red[9] +red[13])*(1.f/128.f);
      out[node*3+2] += (red[2]+red[6]+red[10]+red[14])*(1.f/128.f);
    }
  }
}

// ------- MFMA scatter CIN=96 (r17-measured single-tile form; dual-tile REGRESSED r18:
// 42KB LDS -> 3 blk/CU lost more TLP than phase-halving recovered for the wider Ft).
__global__ __launch_bounds__(256) void k_scat96m(
    const unsigned* __restrict__ Fp, const float4* __restrict__ gw,
    const int4* __restrict__ gmz, const int* __restrict__ row_start,
    unsigned* __restrict__ B, int node_base)
{
  __shared__ __align__(128) _Float16 Wh[64*32];
  __shared__ __align__(128) _Float16 Wl[64*32];
  __shared__ __align__(128) _Float16 Fh[96*32];
  __shared__ __align__(128) _Float16 Fl[96*32];
  __shared__ __align__(16) float4 Sq[32];
  __shared__ __align__(16) int4   Smd[32];

  const int tid  = threadIdx.x;
  const int node = node_base + blockIdx.x;
  const int wv   = tid >> 6;
  const int lane = tid & 63;
  const int frow = lane & 15;
  const int fb   = (lane >> 4) << 4;

  floatx4 acc[6];
  #pragma unroll
  for(int nt=0;nt<6;++nt){ acc[nt][0]=0.f; acc[nt][1]=0.f; acc[nt][2]=0.f; acc[nt][3]=0.f; }

  half8_t hz;
  #pragma unroll
  for(int q8=0;q8<8;++q8) hz[q8] = (_Float16)0;

  const int e0 = row_start[node], e1 = row_start[node+1];

  for(int eb = e0; eb < e1; eb += 32){
    const int n = (e1 - eb < 32) ? (e1 - eb) : 32;
    __syncthreads();
    if(wv == 0){
      if(lane < 32){
        int ei = eb + lane; if(ei >= e1) ei = e1 - 1;
        Sq[lane]  = gw[ei];
        Smd[lane] = gmz[ei];
      }
    } else {
      for(int j = tid - 64; j < 512; j += 192){
        if(j < 256) ((half8_t*)Wh)[j]       = hz;
        else        ((half8_t*)Wl)[j - 256] = hz;
      }
    }
    __syncthreads();
    {
      half8_t h0, l0, h1, l1;
      #pragma unroll
      for(int j=0;j<8;++j){
        const int dst = Smd[wv*8 + j].w;
        const unsigned u = Fp[(size_t)dst*96 + lane];
        h0[j] = lo16(u);
        l0[j] = hi16(u);
        if(lane < 32){
          const unsigned u2 = Fp[(size_t)dst*96 + 64 + lane];
          h1[j] = lo16(u2);
          l1[j] = hi16(u2);
        }
      }
      *(half8_t*)swzp(Fh, (lane<<6) + (wv<<4)) = h0;
      *(half8_t*)swzp(Fl, (lane<<6) + (wv<<4)) = l0;
      if(lane < 32){
        *(half8_t*)swzp(Fh, ((64+lane)<<6) + (wv<<4)) = h1;
        *(half8_t*)swzp(Fl, ((64+lane)<<6) + (wv<<4)) = l1;
      }
    }
    if(lane < 8){
      const int ei = wv*8 + lane;
      if(ei < n){
        const float4 q  = Sq[ei];
        const int4   md = Smd[ei];
        const float zA = __int_as_float(md.x), zB = 1.f - zA;
        #pragma unroll
        for(int t=0;t<8;++t){
          const int   cells = (t < 4) ? md.y : md.z;
          const float zz    = (t < 4) ? zA : zB;
          const int   cell  = (cells >> ((t & 3) * 8)) & 255;
          const float qq    = ((t&3)==0) ? q.x : ((t&3)==1) ? q.y : ((t&3)==2) ? q.z : q.w;
          const float wgt   = qq * zz;
          const _Float16 h  = (_Float16)wgt;
          *(_Float16*)swzp(Wh, (cell<<6) + (ei<<1)) = h;
          *(_Float16*)swzp(Wl, (cell<<6) + (ei<<1)) = (_Float16)(wgt - (float)h);
        }
      }
    }
    __syncthreads();
    const half8_t ah = *(const half8_t*)swzp(Wh, ((wv*16 + frow)<<6) + fb);
    const half8_t al = *(const half8_t*)swzp(Wl, ((wv*16 + frow)<<6) + fb);
    #pragma unroll
    for(int nt=0; nt<6; ++nt){
      const half8_t bh = *(const half8_t*)swzp(Fh, ((nt*16 + frow)<<6) + fb);
      const half8_t bl = *(const half8_t*)swzp(Fl, ((nt*16 + frow)<<6) + fb);
      acc[nt] = __builtin_amdgcn_mfma_f32_16x16x32_f16(ah, bh, acc[nt], 0, 0, 0);
      acc[nt] = __builtin_amdgcn_mfma_f32_16x16x32_f16(al, bh, acc[nt], 0, 0, 0);
      acc[nt] = __builtin_amdgcn_mfma_f32_16x16x32_f16(ah, bl, acc[nt], 0, 0, 0);
    }
  }

  unsigned* Bg = B + (size_t)blockIdx.x*6240;
  #pragma unroll
  for(int nt=0;nt<6;++nt)
    #pragma unroll
    for(int r=0;r<4;++r){
      const int cell = wv*16 + (lane>>4)*4 + r;
      Bg[cell*96 + nt*16 + (lane&15)] = packf(acc[nt][r]);
    }
  if(tid < 96) Bg[6144 + tid] = Fp[(size_t)node*96 + tid];
}

// ------- scatter CIN=13 (RMW form), packed-B epilogue -------------------------------------
__global__ __launch_bounds__(128) void k_scat13(
    const float* __restrict__ feat, const float4* __restrict__ gw,
    const int4* __restrict__ gmz, const int* __restrict__ row_start,
    unsigned* __restrict__ B, int node_base)
{
  constexpr int CIN = 13, BSZ = KK*CIN, ESW = 4, CSTRIDE = BSZ + 8;
  __shared__ __align__(16) float Bl[ESW*CSTRIDE];
  const int tid  = threadIdx.x;
  const int node = node_base + blockIdx.x;

  for(int j = tid; j < ESW*CSTRIDE; j += 128) Bl[j] = 0.f;

  const int e0 = row_start[node], e1 = row_start[node+1];
  const int wv   = tid >> 6;
  const int lane = tid & 63;
  const int slot = lane >> 4;
  const int c    = lane & 15;
  const bool act = (c < CIN);
  float* Bp = Bl + slot*CSTRIDE;
  __syncthreads();

  if(act){
    for(int e = e0 + slot; e < e1; e += ESW){
      const float4 q  = gw[e];
      const int4   md = gmz[e];
      const float zA = __int_as_float(md.x);
      const float z  = wv ? (1.f - zA) : zA;
      const int   cp = wv ? md.z : md.y;
      float v = feat[(size_t)md.w*CIN + c] * z;
      const int b0 = ( cp        & 255)*CIN + c;
      const int b1 = ((cp >> 8)  & 255)*CIN + c;
      const int b2 = ((cp >> 16) & 255)*CIN + c;
      const int b3 = (((unsigned)cp) >> 24)*CIN + c;
      float o0 = Bp[b0], o1 = Bp[b1], o2 = Bp[b2], o3 = Bp[b3];
      o0 = fmaf(q.x, v, o0); o1 = fmaf(q.y, v, o1);
      o2 = fmaf(q.z, v, o2); o3 = fmaf(q.w, v, o3);
      Bp[b0] = o0; Bp[b1] = o1; Bp[b2] = o2; Bp[b3] = o3;
    }
  }
  __syncthreads();

  unsigned* Bg = B + (size_t)blockIdx.x*BSZ;
  for(int j = tid*4; j < BSZ; j += 512){
    float4 a = *(const float4*)&Bl[j];
    #pragma unroll
    for(int k = 1; k < ESW; ++k){
      const float4 t = *(const float4*)&Bl[k*CSTRIDE + j];
      a.x += t.x; a.y += t.y; a.z += t.z; a.w += t.w;
    }
    uint4 o;
    o.x = packf(a.x); o.y = packf(a.y); o.z = packf(a.z); o.w = packf(a.w);
    *(uint4*)&Bg[j] = o;
  }
}

// ---- W pre-pass: transpose + split fp32 -> f16 hi/lo. WhT/WlT layout [64 cols][Ktot k];
// conv weights at k=0..Kcnv-1.
__global__ void k_cvtW(const float* __restrict__ W, _Float16* __restrict__ WhT,
                       _Float16* __restrict__ WlT, int Kcnv, int Ktot)
{
  int idx = blockIdx.x*blockDim.x + threadIdx.x;
  if(idx >= 64*Kcnv) return;
  int o = idx / Kcnv, k = idx - o*Kcnv;
  float w = W[(size_t)k*64 + o];
  _Float16 h = (_Float16)w;
  WhT[(size_t)o*Ktot + k] = h;
  WlT[(size_t)o*Ktot + k] = (_Float16)(w - (float)h);
}

// ---- dense-weight append: dW[cin][64] -> WhT/WlT rows k = koff..koff+Kcin-1 (fusion).
__global__ void k_cvtWd(const float* __restrict__ dW, _Float16* __restrict__ WhT,
                        _Float16* __restrict__ WlT, int Kcin, int Ktot, int koff)
{
  int idx = blockIdx.x*blockDim.x + threadIdx.x;
  if(idx >= 64*Kcin) return;
  int o = idx / Kcin, c = idx - o*Kcin;
  float w = dW[(size_t)c*64 + o];
  _Float16 h = (_Float16)w;
  WhT[(size_t)o*Ktot + koff + c] = h;
  WlT[(size_t)o*Ktot + koff + c] = (_Float16)(w - (float)h);
}

// ---- MFMA GEMM: M=64 tile, packed pre-split A. Kd = TOTAL K (conv cells + fused dense).
__global__ __launch_bounds__(256) void k_gemm_mfma(
    const unsigned* __restrict__ Ap, const _Float16* __restrict__ WhT,
    const _Float16* __restrict__ WlT, float* __restrict__ P,
    int M, int Kd, int node_base, int ksteps_per)
{
  __shared__ __align__(128) _Float16 Ah[64*32];
  __shared__ __align__(128) _Float16 Al[64*32];
  __shared__ __align__(128) _Float16 Bh[64*32];
  __shared__ __align__(128) _Float16 Blo[64*32];
  const int tid = threadIdx.x;
  const int mbase = blockIdx.x * 64;
  const int s = blockIdx.y;
  const int kt0 = s * ksteps_per * 32;
  const int kt1 = min(Kd, kt0 + ksteps_per*32);
  const int wv = tid >> 6, lane = tid & 63;
  const int row  = tid >> 2;          // staging row (A row / W col), 0..63
  const int useg = (tid & 3) * 8;     // u32 seg (8 u32 per thread) within 32-wide tile
  const int sb   = (tid & 3) << 4;    // staging byte col (16B per thread per buf)
  const int frow = lane & 15;
  const int fb   = (lane >> 4) << 4;  // frag byte col

  floatx4 acc[4];
  #pragma unroll
  for(int c=0;c<4;++c){ acc[c][0]=0.f; acc[c][1]=0.f; acc[c][2]=0.f; acc[c][3]=0.f; }

  const int grow = mbase + row;
  const unsigned* Arow = (grow < M) ? (Ap + (size_t)grow*Kd) : nullptr;
  const _Float16* WhRow = WhT + (size_t)row*Kd;
  const _Float16* WlRow = WlT + (size_t)row*Kd;

  for(int kt = kt0; kt < kt1; kt += 32){
    unsigned au[8];
    if(Arow){
      *(uint4*)&au[0] = *(const uint4*)(Arow + kt + useg);
      *(uint4*)&au[4] = *(const uint4*)(Arow + kt + useg + 4);
    } else {
      #pragma unroll
      for(int j=0;j<8;++j) au[j] = 0u;
    }
    half8_t hv, lv;
    #pragma unroll
    for(int j=0;j<8;++j){
      hv[j] = lo16(au[j]);
      lv[j] = hi16(au[j]);
    }
    half8_t wh = *(const half8_t*)(WhRow + kt + useg);
    half8_t wl = *(const half8_t*)(WlRow + kt + useg);
    __syncthreads();                        // previous iter's frag reads complete
    *(half8_t*)swzp(Ah,  (row<<6) + sb) = hv;
    *(half8_t*)swzp(Al,  (row<<6) + sb) = lv;
    *(half8_t*)swzp(Bh,  (row<<6) + sb) = wh;
    *(half8_t*)swzp(Blo, (row<<6) + sb) = wl;
    __syncthreads();                        // staged tile visible
    const half8_t ah = *(const half8_t*)swzp(Ah, ((wv*16 + frow)<<6) + fb);
    const half8_t al = *(const half8_t*)swzp(Al, ((wv*16 + frow)<<6) + fb);
    #pragma unroll
    for(int c=0;c<4;++c){
      const half8_t bh = *(const half8_t*)swzp(Bh,  ((c*16 + frow)<<6) + fb);
      const half8_t bl = *(const half8_t*)swzp(Blo, ((c*16 + frow)<<6) + fb);
      acc[c] = __builtin_amdgcn_mfma_f32_16x16x32_f16(ah, bh, acc[c], 0, 0, 0);
      acc[c] = __builtin_amdgcn_mfma_f32_16x16x32_f16(al, bh, acc[c], 0, 0, 0);
      acc[c] = __builtin_amdgcn_mfma_f32_16x16x32_f16(ah, bl, acc[c], 0, 0, 0);
    }
  }

  const int prow0 = mbase + wv*16 + (lane>>4)*4;
  const int pcol  = lane & 15;
  #pragma unroll
  for(int c=0;c<4;++c){
    #pragma unroll
    for(int r=0;r<4;++r){
      const int rr = prow0 + r;
      if(rr < M)
        P[((size_t)s*NPTS + node_base + rr)*64 + c*16 + pcol] = acc[c][r];
    }
  }
}

// ---- combine partials: x[node*ldout+colofs+o] += sum_s P[s][node][o]
template<int S>
__global__ void k_combine(const float* __restrict__ P, float* __restrict__ x,
                          int ldout, int colofs)
{
  int idx = blockIdx.x*blockDim.x + threadIdx.x;
  if(idx >= NPTS*16) return;
  int node = idx >> 4, c4 = (idx & 15) * 4;
  float4 s = *(const float4*)(P + (size_t)node*64 + c4);
  #pragma unroll
  for(int k=1;k<S;++k){
    float4 t = *(const float4*)(P + ((size_t)k*NPTS + node)*64 + c4);
    s.x+=t.x; s.y+=t.y; s.z+=t.z; s.w+=t.w;
  }
  float* xp = x + (size_t)node*ldout + colofs + c4;
  float4 o = *(float4*)xp;
  o.x+=s.x; o.y+=s.y; o.z+=s.z; o.w+=s.w;
  *(float4*)xp = o;
}

// ---------------- dense/bias paths ----------------
__global__ void k_dense0(const float* __restrict__ f, const float* __restrict__ dW,
                         const float* __restrict__ db, const float* __restrict__ cb0,
                         float* __restrict__ out)
{
  int idx = blockIdx.x*blockDim.x + threadIdx.x;
  if(idx >= NPTS*96) return;
  int i = idx/96, c = idx - i*96;
  if(c < 64){ out[idx] = cb0[c]; return; }
  int o = c - 64;
  float s = db[o];
  const float* row = f + (size_t)i*13;
  #pragma unroll
  for(int j=0;j<13;++j) s = fmaf(row[j], dW[j*32+o], s);
  out[idx] = s;
}

// bias init (dense matvec now fused into the GEMM K): x = db + cb (+ resid)
__global__ void k_bias(const float* __restrict__ db, const float* __restrict__ cb,
                       const float* __restrict__ resid, float* __restrict__ out)
{
  int idx = blockIdx.x*blockDim.x + threadIdx.x;
  if(idx >= NPTS*64) return;
  int o = idx & 63;
  float s = db[o] + cb[o];
  if(resid) s += resid[idx];
  out[idx] = s;
}

__global__ void k_dense3(const float* __restrict__ x2, const float* __restrict__ dW,
                         const float* __restrict__ db, const float* __restrict__ cb,
                         float* __restrict__ out)
{
  int idx = blockIdx.x*blockDim.x + threadIdx.x;
  if(idx >= NREAL*3) return;
  int i = idx/3, o = idx - i*3;
  float s = db[o] + cb[o];
  const float* row = x2 + (size_t)i*64;
  for(int c=0;c<64;++c) s = fmaf(fmaxf(row[c],0.f), dW[c*3+o], s);
  out[idx] = s * (1.f/128.f);
}

// ---------------- host ----------------
static inline size_t alup(size_t x){ return (x + 255) & ~(size_t)255; }

static inline int calc_rows(size_t bcap, int u32row, int want){
  size_t perrow = (size_t)u32row * 4;
  size_t r = (perrow > 0) ? bcap / perrow : 0;
  if(r >= (size_t)want) return want;
  r = (r / 128) * 128;
  if(r < 128) r = 128;
  return (int)r;
}

extern "C" void kernel_launch(void* const* d_in, const int* in_sizes, int n_in,
                              void* d_out, int out_size, void* d_ws, size_t ws_size,
                              hipStream_t stream)
{
  const float* pos   = (const float*)d_in[0];
  const float* feats = (const float*)d_in[1];
  const int*   esrc  = (const int*)d_in[2];
  const int*   edst  = (const int*)d_in[3];
  const float* c0w = (const float*)d_in[4];
  const float* c0b = (const float*)d_in[5];
  const float* d0w = (const float*)d_in[6];
  const float* d0b = (const float*)d_in[7];
  const float* c1w = (const float*)d_in[8];
  const float* c1b = (const float*)d_in[9];
  const float* d1w = (const float*)d_in[10];
  const float* d1b = (const float*)d_in[11];
  const float* c2w = (const float*)d_in[12];
  const float* c2b = (const float*)d_in[13];
  const float* d2w = (const float*)d_in[14];
  const float* d2b = (const float*)d_in[15];
  const float* c3w = (const float*)d_in[16];
  const float* c3b = (const float*)d_in[17];
  const float* d3w = (const float*)d_in[18];
  const float* d3b = (const float*)d_in[19];
  float* out = (float*)d_out;

  char* w = (char*)d_ws;
  size_t off = 0;
  float* f  = (float*)(w+off); off += alup((size_t)NPTS*13*4);
  float* x0 = (float*)(w+off); off += alup((size_t)NPTS*96*4);
  float* x1 = (float*)(w+off); off += alup((size_t)NPTS*64*4);
  float* x2 = (float*)(w+off); off += alup((size_t)NPTS*64*4);
  int* row_start = (int*)(w+off); off += alup((size_t)(NPTS+1)*4);
  int* ereal = (int*)(w+off);     off += alup(16);
  float4* gw = (float4*)(w+off);  off += alup((size_t)EPAD*16);     // per-edge xy weights
  int4*  gmz = (int4*)(w+off);    off += alup((size_t)EPAD*16);     // per-edge zA+cells+dst
  float* P  = (float*)(w+off); off += alup((size_t)8*NPTS*64*4);    // split-K partials
  _Float16* whT = (_Float16*)(w+off); off += alup((size_t)64*6400*2); // W hi (transposed, Ktot<=6240)
  _Float16* wlT = (_Float16*)(w+off); off += alup((size_t)64*6400*2); // W lo (transposed)
  unsigned* Fp0 = (unsigned*)(w+off); off += alup((size_t)NPTS*96*4); // packed pre-split feats (96ch)
  unsigned* Fp1 = (unsigned*)(w+off); off += alup((size_t)NPTS*64*4); // packed pre-split feats (64ch)
  unsigned* B = (unsigned*)(w+off);                                   // packed pre-split B
  size_t bcap = (ws_size > off) ? (ws_size - off) : 0;

  k_find_ereal<<<1,1,0,stream>>>(edst, ereal);
  k_csr<<<(NPTS+1+255)/256,256,0,stream>>>(esrc, ereal, row_start);
  k_build_f<<<(NPTS*13+255)/256,256,0,stream>>>(feats, f);
  k_geom<<<(EPAD+255)/256,256,0,stream>>>(pos, esrc, edst, gw, gmz);

  // ---- layer 0: x0[:,0:64] = cconv0(f)+c0b ; x0[:,64:96] = f@d0w+d0b  (chunk 8192)
  // split-K 8->4 (ktiles_per=7 covers 26 ksteps); dropped splits only wrote +0 -> exact.
  k_dense0<<<(NPTS*96+255)/256,256,0,stream>>>(f, d0w, d0b, c0b, x0);
  {
    k_cvtW<<<(64*832+255)/256,256,0,stream>>>(c0w, whT, wlT, 832, 832);
    int rows = calc_rows(bcap, 832, 8192);
    for(int base = 0; base < NPTS; base += rows){
      int m = (NPTS - base < rows) ? (NPTS - base) : rows;
      k_scat13<<<m,128,0,stream>>>(f, gw, gmz, row_start, B, base);
      k_gemm_mfma<<<dim3((m+63)/64, 4),256,0,stream>>>(B, whT, wlT, P, m, 832, base, 7);
    }
    k_combine<4><<<(NPTS*16+255)/256,256,0,stream>>>(P, x0, 96, 0);
  }

  // ---- layer 1: x1 = cconv1(relu(x0)) + relu(x0)@d1w + d1b + c1b
  //      dense fused into GEMM: Kd = 6144 + 96
  k_bias<<<(NPTS*64+255)/256,256,0,stream>>>(d1b, c1b, nullptr, x1);
  {
    k_cvtW<<<(64*6144+255)/256,256,0,stream>>>(c1w, whT, wlT, 6144, 6240);
    k_cvtWd<<<(64*96+255)/256,256,0,stream>>>(d1w, whT, wlT, 96, 6240, 6144);
    k_cvtF<<<(NPTS*96+255)/256,256,0,stream>>>(x0, Fp0, NPTS*96);
    int rows = calc_rows(bcap, 6240, 4096);
    for(int base = 0; base < NPTS; base += rows){
      int m = (NPTS - base < rows) ? (NPTS - base) : rows;
      k_scat96m<<<m,256,0,stream>>>(Fp0, gw, gmz, row_start, B, base);
      k_gemm_mfma<<<dim3((m+63)/64, 8),256,0,stream>>>(B, whT, wlT, P, m, 6240, base, 25);
    }
    k_combine<8><<<(NPTS*16+255)/256,256,0,stream>>>(P, x1, 64, 0);
  }

  // ---- layer 2: x2 = cconv2(relu(x1)) + relu(x1)@d2w + d2b + c2b + x1
  //      dense fused into GEMM: Kd = 4096 + 64
  k_bias<<<(NPTS*64+255)/256,256,0,stream>>>(d2b, c2b, x1, x2);
  {
    k_cvtW<<<(64*4096+255)/256,256,0,stream>>>(c2w, whT, wlT, 4096, 4160);
    k_cvtWd<<<(64*64+255)/256,256,0,stream>>>(d2w, whT, wlT, 64, 4160, 4096);
    k_cvtF<<<(NPTS*64+255)/256,256,0,stream>>>(x1, Fp1, NPTS*64);
    int rows = calc_rows(bcap, 4160, 4096);
    for(int base = 0; base < NPTS; base += rows){
      int m = (NPTS - base < rows) ? (NPTS - base) : rows;
      k_scat64m<0><<<m,256,0,stream>>>(Fp1, gw, gmz, row_start, B, base, nullptr, nullptr);
      k_gemm_mfma<<<dim3((m+63)/64, 8),256,0,stream>>>(B, whT, wlT, P, m, 4160, base, 17);
    }
    k_combine<8><<<(NPTS*16+255)/256,256,0,stream>>>(P, x2, 64, 0);
  }

  // ---- layer 3 (fused): out = dense3 part, then scatter adds conv3 GEMV directly
  k_dense3<<<(NREAL*3+255)/256,256,0,stream>>>(x2, d3w, d3b, c3b, out);
  k_cvtF<<<(NPTS*64+255)/256,256,0,stream>>>(x2, Fp1, NPTS*64);
  k_scat64m<1><<<NPTS,256,0,stream>>>(Fp1, gw, gmz, row_start, nullptr, 0, c3w, out);
}

// Round 20
// 872.569 us; speedup vs baseline: 1.0210x; 1.0100x over previous
//
#include <hip/hip_runtime.h>
#include <math.h>

#define NPTS   20001
#define NREAL  20000
#define EPAD   1200000
#define KK     64
#define RADF   0.1125f

typedef _Float16 half8_t __attribute__((ext_vector_type(8)));
typedef float    floatx4 __attribute__((ext_vector_type(4)));

__device__ __forceinline__ float sgnf(float v){ return v>0.f ? 1.f : (v<0.f ? -1.f : 0.f); }
__device__ __forceinline__ _Float16 lo16(unsigned u){ return __builtin_bit_cast(_Float16, (unsigned short)(u & 0xffffu)); }
__device__ __forceinline__ _Float16 hi16(unsigned u){ return __builtin_bit_cast(_Float16, (unsigned short)(u >> 16)); }
// deterministic fp32 -> packed f16 hi/lo split (hi in low 16 bits).
__device__ __forceinline__ unsigned packf(float v){
  _Float16 h = (_Float16)v;
  _Float16 l = (_Float16)(v - (float)h);
  return (unsigned)__builtin_bit_cast(unsigned short, h)
       | ((unsigned)__builtin_bit_cast(unsigned short, l) << 16);
}

// byte-offset XOR swizzle for [rows][32]-half (64B-row) LDS tiles.
__device__ __forceinline__ void* swzp(void* base, int byteoff){
  return (void*)((char*)base + (byteoff ^ (((byteoff >> 6) & 7) << 4)));
}
__device__ __forceinline__ const void* swzp(const void* base, int byteoff){
  return (const void*)((const char*)base + (byteoff ^ (((byteoff >> 6) & 7) << 4)));
}

// ---------------- CSR build (edge_src is sorted; pad edges have dst==NREAL) ----------------
__global__ void k_find_ereal(const int* __restrict__ dst, int* __restrict__ ereal){
  int lo=0, hi=EPAD;
  while(lo<hi){ int mid=(lo+hi)>>1; if(dst[mid]==NREAL) hi=mid; else lo=mid+1; }
  *ereal = lo;
}

__global__ void k_csr(const int* __restrict__ src, const int* __restrict__ erealp,
                      int* __restrict__ row_start){
  int i = blockIdx.x*blockDim.x + threadIdx.x;
  if(i > NPTS) return;
  int E = *erealp;
  int lo=0, hi=E;
  while(lo<hi){ int mid=(lo+hi)>>1; if(src[mid] < i) lo=mid+1; else hi=mid; }
  row_start[i] = lo;
}

__global__ void k_build_f(const float* __restrict__ feats, float* __restrict__ f){
  int idx = blockIdx.x*blockDim.x + threadIdx.x;
  if(idx >= NPTS*13) return;
  int i = idx/13, c = idx - i*13;
  f[idx] = (c==0) ? 1.f : feats[i*12 + (c-1)];
}

// ---------------- per-edge geometry (exact port of ball_to_cube + window) ----------------
__device__ __forceinline__ void edge_geom(float ox, float oy, float oz,
                                          float& win, float& t0, float& t1, float& t2, int& f0p){
  const float eps = 1e-9f;
  float sq = ox*ox + oy*oy + oz*oz;
  float u = 1.f - sq;
  win = fminf(fmaxf(u*u*u, 0.f), 1.f);
  float norm = sqrtf(sq + eps);
  float rxy2 = ox*ox + oy*oy;
  bool polar = (1.25f*oz*oz > rxy2);
  float s_p = sqrtf(3.f*norm/(norm + fabsf(oz) + eps));
  float s_n = norm / sqrtf(rxy2 + eps);
  float s = polar ? s_p : s_n;
  float xc = ox*s, yc = oy*s;
  float zc = polar ? sgnf(oz)*norm : 1.5f*oz;
  if(sq < 1e-12f){ xc = 0.f; yc = 0.f; zc = 0.f; }
  float r = sqrtf(xc*xc + yc*yc + eps);
  bool c1 = fabsf(xc) >= fabsf(yc);
  float xs = (fabsf(xc) < eps) ? eps : xc;
  float ys = (fabsf(yc) < eps) ? eps : yc;
  const float fop = 1.2732395447351628f; // float32(4/pi)
  float a = c1 ? sgnf(xc)*r : sgnf(yc)*r*fop*atanf(xc/ys);
  float b = c1 ? sgnf(xc)*r*fop*atanf(yc/xs) : sgnf(yc)*r;
  if(xc*xc + yc*yc < 1e-12f){ a = 0.f; b = 0.f; }
  float g0 = fminf(fmaxf((a *0.5f+0.5f)*3.f, 0.f), 3.f);
  float g1 = fminf(fmaxf((b *0.5f+0.5f)*3.f, 0.f), 3.f);
  float g2 = fminf(fmaxf((zc*0.5f+0.5f)*3.f, 0.f), 3.f);
  float f00 = floorf(g0), f01 = floorf(g1), f02 = floorf(g2);
  t0 = g0 - f00; t1 = g1 - f01; t2 = g2 - f02;
  f0p = (int)f00 | ((int)f01 << 2) | ((int)f02 << 4);
}

// ---- k_geom: per-edge staged data, computed ONCE (shared by all 4 scatter layers).
__global__ __launch_bounds__(256) void k_geom(const float* __restrict__ pos,
    const int* __restrict__ esrc, const int* __restrict__ edst,
    float4* __restrict__ gw, int4* __restrict__ gmz)
{
  int e = blockIdx.x*blockDim.x + threadIdx.x;
  if(e >= EPAD) return;
  const int sn = esrc[e], d = edst[e];
  const float ox = (pos[d*3+0]-pos[sn*3+0])/RADF;
  const float oy = (pos[d*3+1]-pos[sn*3+1])/RADF;
  const float oz = (pos[d*3+2]-pos[sn*3+2])/RADF;
  float win, t0, t1, t2; int f0p;
  edge_geom(ox, oy, oz, win, t0, t1, t2, f0p);
  const int i0 = f0p & 3, i1 = (f0p>>2) & 3, i2 = f0p >> 4;
  const int X0 = i0 << 4, X1 = ((i0+1)&3) << 4;
  const int Y0 = i1 << 2, Y1 = ((i1+1)&3) << 2;
  const int Z0 = i2, Z1 = (i2+1) & 3;
  const float wx0 = win*(1.f-t0), wx1 = win*t0;
  const float wy0 = 1.f-t1, wy1 = t1;
  const float wz0 = 1.f-t2, wz1 = t2;
  gw[e] = make_float4(wx0*wy0, wx0*wy1, wx1*wy0, wx1*wy1);
  const int p0 = Z0 & 1;
  const float zA = p0 ? wz1 : wz0;                  // weight for parity-0 (even z) cell
  const int   cA = p0 ? Z1 : Z0;                    // even-z cell
  const int   cB = p0 ? Z0 : Z1;                    // odd-z cell
  const int cells0 = (X0|Y0|cA) | ((X0|Y1|cA)<<8) | ((X1|Y0|cA)<<16) | ((X1|Y1|cA)<<24);
  const int cells1 = (X0|Y0|cB) | ((X0|Y1|cB)<<8) | ((X1|Y0|cB)<<16) | ((X1|Y1|cB)<<24);
  gmz[e] = make_int4(__float_as_int(zA), cells0, cells1, d);
}

// ------- MFMA scatter CIN=64 (v7): 64-EDGE PHASES via dual 32-tiles (r17/r18: 124->111us).
template<int OUT3>
__global__ __launch_bounds__(256) void k_scat64m(
    const unsigned* __restrict__ Fp, const float4* __restrict__ gw,
    const int4* __restrict__ gmz, const int* __restrict__ row_start,
    unsigned* __restrict__ B, int node_base,
    const float* __restrict__ W3, float* __restrict__ out)
{
  __shared__ __align__(128) _Float16 Wh0[64*32];
  __shared__ __align__(128) _Float16 Wl0[64*32];
  __shared__ __align__(128) _Float16 Wh1[64*32];
  __shared__ __align__(128) _Float16 Wl1[64*32];
  __shared__ __align__(128) _Float16 Fh0[64*32];
  __shared__ __align__(128) _Float16 Fl0[64*32];
  __shared__ __align__(128) _Float16 Fh1[64*32];
  __shared__ __align__(128) _Float16 Fl1[64*32];
  __shared__ __align__(16) float4 Sq[64];
  __shared__ __align__(16) int4   Smd[64];
  __shared__ float red[16];

  const int tid  = threadIdx.x;
  const int node = node_base + blockIdx.x;
  const int wv   = tid >> 6;
  const int lane = tid & 63;
  const int frow = lane & 15;
  const int fb   = (lane >> 4) << 4;   // frag col byte offset

  floatx4 acc[4];
  #pragma unroll
  for(int nt=0;nt<4;++nt){ acc[nt][0]=0.f; acc[nt][1]=0.f; acc[nt][2]=0.f; acc[nt][3]=0.f; }

  half8_t hz;
  #pragma unroll
  for(int q8=0;q8<8;++q8) hz[q8] = (_Float16)0;

  const int e0 = row_start[node], e1 = row_start[node+1];

  for(int eb = e0; eb < e1; eb += 64){
    const int n = (e1 - eb < 64) ? (e1 - eb) : 64;
    __syncthreads();                       // prior frag + Sq/Smd reads complete
    if(wv == 0){
      int ei = eb + lane; if(ei >= e1) ei = e1 - 1;   // clamp tail (scatter guarded by n)
      Sq[lane]  = gw[ei];
      Smd[lane] = gmz[ei];
    } else {
      for(int j = tid - 64; j < 1024; j += 192){
        if(j < 256)       ((half8_t*)Wh0)[j]       = hz;
        else if(j < 512)  ((half8_t*)Wl0)[j - 256] = hz;
        else if(j < 768)  ((half8_t*)Wh1)[j - 512] = hz;
        else              ((half8_t*)Wl1)[j - 768] = hz;
      }
    }
    __syncthreads();                       // Sq/Smd + zeroed Wt visible
    {
      half8_t h0r, l0r, h1r, l1r;
      #pragma unroll
      for(int j=0;j<8;++j){
        const int d0 = Smd[wv*8 + j].w;
        const unsigned u0 = Fp[(size_t)d0*64 + lane];
        h0r[j] = lo16(u0);
        l0r[j] = hi16(u0);
        const int d1 = Smd[32 + wv*8 + j].w;
        const unsigned u1 = Fp[(size_t)d1*64 + lane];
        h1r[j] = lo16(u1);
        l1r[j] = hi16(u1);
      }
      *(half8_t*)swzp(Fh0, (lane<<6) + (wv<<4)) = h0r;
      *(half8_t*)swzp(Fl0, (lane<<6) + (wv<<4)) = l0r;
      *(half8_t*)swzp(Fh1, (lane<<6) + (wv<<4)) = h1r;
      *(half8_t*)swzp(Fl1, (lane<<6) + (wv<<4)) = l1r;
    }
    if(lane < 16){
      const int ei = wv*16 + lane;         // 4 waves x 16 = 64 edges
      if(ei < n){
        const float4 q  = Sq[ei];
        const int4   md = Smd[ei];
        const float zA = __int_as_float(md.x), zB = 1.f - zA;
        _Float16* Whp = (ei < 32) ? Wh0 : Wh1;
        _Float16* Wlp = (ei < 32) ? Wl0 : Wl1;
        const int ep = ei & 31;
        #pragma unroll
        for(int t=0;t<8;++t){
          const int   cells = (t < 4) ? md.y : md.z;
          const float zz    = (t < 4) ? zA : zB;
          const int   cell  = (cells >> ((t & 3) * 8)) & 255;
          const float qq    = ((t&3)==0) ? q.x : ((t&3)==1) ? q.y : ((t&3)==2) ? q.z : q.w;
          const float wgt   = qq * zz;
          const _Float16 h  = (_Float16)wgt;
          *(_Float16*)swzp(Whp, (cell<<6) + (ep<<1)) = h;
          *(_Float16*)swzp(Wlp, (cell<<6) + (ep<<1)) = (_Float16)(wgt - (float)h);
        }
      }
    }
    __syncthreads();                       // both tiles staged
    {
      const half8_t ah = *(const half8_t*)swzp(Wh0, ((wv*16 + frow)<<6) + fb);
      const half8_t al = *(const half8_t*)swzp(Wl0, ((wv*16 + frow)<<6) + fb);
      #pragma unroll
      for(int nt=0; nt<4; ++nt){
        const half8_t bh = *(const half8_t*)swzp(Fh0, ((nt*16 + frow)<<6) + fb);
        const half8_t bl = *(const half8_t*)swzp(Fl0, ((nt*16 + frow)<<6) + fb);
        acc[nt] = __builtin_amdgcn_mfma_f32_16x16x32_f16(ah, bh, acc[nt], 0, 0, 0);
        acc[nt] = __builtin_amdgcn_mfma_f32_16x16x32_f16(al, bh, acc[nt], 0, 0, 0);
        acc[nt] = __builtin_amdgcn_mfma_f32_16x16x32_f16(ah, bl, acc[nt], 0, 0, 0);
      }
    }
    {
      const half8_t ah = *(const half8_t*)swzp(Wh1, ((wv*16 + frow)<<6) + fb);
      const half8_t al = *(const half8_t*)swzp(Wl1, ((wv*16 + frow)<<6) + fb);
      #pragma unroll
      for(int nt=0; nt<4; ++nt){
        const half8_t bh = *(const half8_t*)swzp(Fh1, ((nt*16 + frow)<<6) + fb);
        const half8_t bl = *(const half8_t*)swzp(Fl1, ((nt*16 + frow)<<6) + fb);
        acc[nt] = __builtin_amdgcn_mfma_f32_16x16x32_f16(ah, bh, acc[nt], 0, 0, 0);
        acc[nt] = __builtin_amdgcn_mfma_f32_16x16x32_f16(al, bh, acc[nt], 0, 0, 0);
        acc[nt] = __builtin_amdgcn_mfma_f32_16x16x32_f16(ah, bl, acc[nt], 0, 0, 0);
      }
    }
  }

  if(!OUT3){
    unsigned* Bg = B + (size_t)blockIdx.x*4160;
    #pragma unroll
    for(int nt=0;nt<4;++nt)
      #pragma unroll
      for(int r=0;r<4;++r){
        const int cell = wv*16 + (lane>>4)*4 + r;
        Bg[cell*64 + nt*16 + (lane&15)] = packf(acc[nt][r]);
      }
    if(tid < 64) Bg[4096 + tid] = Fp[(size_t)node*64 + tid];
  } else {
    float s0=0.f, s1=0.f, s2=0.f;
    #pragma unroll
    for(int nt=0;nt<4;++nt){
      #pragma unroll
      for(int r=0;r<4;++r){
        const int cell = wv*16 + (lane>>4)*4 + r;
        const int j3   = (cell*64 + nt*16 + (lane&15)) * 3;
        const float v  = acc[nt][r];
        s0 = fmaf(v, W3[j3+0], s0);
        s1 = fmaf(v, W3[j3+1], s1);
        s2 = fmaf(v, W3[j3+2], s2);
      }
    }
    #pragma unroll
    for(int off = 32; off > 0; off >>= 1){
      s0 += __shfl_down(s0, off);
      s1 += __shfl_down(s1, off);
      s2 += __shfl_down(s2, off);
    }
    if(lane == 0){
      red[wv*4+0] = s0; red[wv*4+1] = s1; red[wv*4+2] = s2;
    }
    __syncthreads();
    if(tid == 0 && node < NREAL){
      out[node*3+0] += (red[0]+red[4]+red[8] +red[12])*(1.f/128.f);
      out[node*3+1] += (red[1]+red[5]+red[9] +red[13])*(1.f/128.f);
      out[node*3+2] += (red[2]+red[6]+red[10]+red[14])*(1.f/128.f);
    }
  }
}

// ------- MFMA scatter CIN=96 (r17-measured single-tile form) -------------------------------
__global__ __launch_bounds__(256) void k_scat96m(
    const unsigned* __restrict__ Fp, const float4* __restrict__ gw,
    const int4* __restrict__ gmz, const int* __restrict__ row_start,
    unsigned* __restrict__ B, int node_base)
{
  __shared__ __align__(128) _Float16 Wh[64*32];
  __shared__ __align__(128) _Float16 Wl[64*32];
  __shared__ __align__(128) _Float16 Fh[96*32];
  __shared__ __align__(128) _Float16 Fl[96*32];
  __shared__ __align__(16) float4 Sq[32];
  __shared__ __align__(16) int4   Smd[32];

  const int tid  = threadIdx.x;
  const int node = node_base + blockIdx.x;
  const int wv   = tid >> 6;
  const int lane = tid & 63;
  const int frow = lane & 15;
  const int fb   = (lane >> 4) << 4;

  floatx4 acc[6];
  #pragma unroll
  for(int nt=0;nt<6;++nt){ acc[nt][0]=0.f; acc[nt][1]=0.f; acc[nt][2]=0.f; acc[nt][3]=0.f; }

  half8_t hz;
  #pragma unroll
  for(int q8=0;q8<8;++q8) hz[q8] = (_Float16)0;

  const int e0 = row_start[node], e1 = row_start[node+1];

  for(int eb = e0; eb < e1; eb += 32){
    const int n = (e1 - eb < 32) ? (e1 - eb) : 32;
    __syncthreads();
    if(wv == 0){
      if(lane < 32){
        int ei = eb + lane; if(ei >= e1) ei = e1 - 1;
        Sq[lane]  = gw[ei];
        Smd[lane] = gmz[ei];
      }
    } else {
      for(int j = tid - 64; j < 512; j += 192){
        if(j < 256) ((half8_t*)Wh)[j]       = hz;
        else        ((half8_t*)Wl)[j - 256] = hz;
      }
    }
    __syncthreads();
    {
      half8_t h0, l0, h1, l1;
      #pragma unroll
      for(int j=0;j<8;++j){
        const int dst = Smd[wv*8 + j].w;
        const unsigned u = Fp[(size_t)dst*96 + lane];
        h0[j] = lo16(u);
        l0[j] = hi16(u);
        if(lane < 32){
          const unsigned u2 = Fp[(size_t)dst*96 + 64 + lane];
          h1[j] = lo16(u2);
          l1[j] = hi16(u2);
        }
      }
      *(half8_t*)swzp(Fh, (lane<<6) + (wv<<4)) = h0;
      *(half8_t*)swzp(Fl, (lane<<6) + (wv<<4)) = l0;
      if(lane < 32){
        *(half8_t*)swzp(Fh, ((64+lane)<<6) + (wv<<4)) = h1;
        *(half8_t*)swzp(Fl, ((64+lane)<<6) + (wv<<4)) = l1;
      }
    }
    if(lane < 8){
      const int ei = wv*8 + lane;
      if(ei < n){
        const float4 q  = Sq[ei];
        const int4   md = Smd[ei];
        const float zA = __int_as_float(md.x), zB = 1.f - zA;
        #pragma unroll
        for(int t=0;t<8;++t){
          const int   cells = (t < 4) ? md.y : md.z;
          const float zz    = (t < 4) ? zA : zB;
          const int   cell  = (cells >> ((t & 3) * 8)) & 255;
          const float qq    = ((t&3)==0) ? q.x : ((t&3)==1) ? q.y : ((t&3)==2) ? q.z : q.w;
          const float wgt   = qq * zz;
          const _Float16 h  = (_Float16)wgt;
          *(_Float16*)swzp(Wh, (cell<<6) + (ei<<1)) = h;
          *(_Float16*)swzp(Wl, (cell<<6) + (ei<<1)) = (_Float16)(wgt - (float)h);
        }
      }
    }
    __syncthreads();
    const half8_t ah = *(const half8_t*)swzp(Wh, ((wv*16 + frow)<<6) + fb);
    const half8_t al = *(const half8_t*)swzp(Wl, ((wv*16 + frow)<<6) + fb);
    #pragma unroll
    for(int nt=0; nt<6; ++nt){
      const half8_t bh = *(const half8_t*)swzp(Fh, ((nt*16 + frow)<<6) + fb);
      const half8_t bl = *(const half8_t*)swzp(Fl, ((nt*16 + frow)<<6) + fb);
      acc[nt] = __builtin_amdgcn_mfma_f32_16x16x32_f16(ah, bh, acc[nt], 0, 0, 0);
      acc[nt] = __builtin_amdgcn_mfma_f32_16x16x32_f16(al, bh, acc[nt], 0, 0, 0);
      acc[nt] = __builtin_amdgcn_mfma_f32_16x16x32_f16(ah, bl, acc[nt], 0, 0, 0);
    }
  }

  unsigned* Bg = B + (size_t)blockIdx.x*6240;
  #pragma unroll
  for(int nt=0;nt<6;++nt)
    #pragma unroll
    for(int r=0;r<4;++r){
      const int cell = wv*16 + (lane>>4)*4 + r;
      Bg[cell*96 + nt*16 + (lane&15)] = packf(acc[nt][r]);
    }
  if(tid < 96) Bg[6144 + tid] = Fp[(size_t)node*96 + tid];
}

// ------- scatter CIN=13 (RMW form), packed-B epilogue -------------------------------------
__global__ __launch_bounds__(128) void k_scat13(
    const float* __restrict__ feat, const float4* __restrict__ gw,
    const int4* __restrict__ gmz, const int* __restrict__ row_start,
    unsigned* __restrict__ B, int node_base)
{
  constexpr int CIN = 13, BSZ = KK*CIN, ESW = 4, CSTRIDE = BSZ + 8;
  __shared__ __align__(16) float Bl[ESW*CSTRIDE];
  const int tid  = threadIdx.x;
  const int node = node_base + blockIdx.x;

  for(int j = tid; j < ESW*CSTRIDE; j += 128) Bl[j] = 0.f;

  const int e0 = row_start[node], e1 = row_start[node+1];
  const int wv   = tid >> 6;
  const int lane = tid & 63;
  const int slot = lane >> 4;
  const int c    = lane & 15;
  const bool act = (c < CIN);
  float* Bp = Bl + slot*CSTRIDE;
  __syncthreads();

  if(act){
    for(int e = e0 + slot; e < e1; e += ESW){
      const float4 q  = gw[e];
      const int4   md = gmz[e];
      const float zA = __int_as_float(md.x);
      const float z  = wv ? (1.f - zA) : zA;
      const int   cp = wv ? md.z : md.y;
      float v = feat[(size_t)md.w*CIN + c] * z;
      const int b0 = ( cp        & 255)*CIN + c;
      const int b1 = ((cp >> 8)  & 255)*CIN + c;
      const int b2 = ((cp >> 16) & 255)*CIN + c;
      const int b3 = (((unsigned)cp) >> 24)*CIN + c;
      float o0 = Bp[b0], o1 = Bp[b1], o2 = Bp[b2], o3 = Bp[b3];
      o0 = fmaf(q.x, v, o0); o1 = fmaf(q.y, v, o1);
      o2 = fmaf(q.z, v, o2); o3 = fmaf(q.w, v, o3);
      Bp[b0] = o0; Bp[b1] = o1; Bp[b2] = o2; Bp[b3] = o3;
    }
  }
  __syncthreads();

  unsigned* Bg = B + (size_t)blockIdx.x*BSZ;
  for(int j = tid*4; j < BSZ; j += 512){
    float4 a = *(const float4*)&Bl[j];
    #pragma unroll
    for(int k = 1; k < ESW; ++k){
      const float4 t = *(const float4*)&Bl[k*CSTRIDE + j];
      a.x += t.x; a.y += t.y; a.z += t.z; a.w += t.w;
    }
    uint4 o;
    o.x = packf(a.x); o.y = packf(a.y); o.z = packf(a.z); o.w = packf(a.w);
    *(uint4*)&Bg[j] = o;
  }
}

// ---- W pre-pass: transpose + split fp32 -> f16 hi/lo. WhT/WlT layout [64 cols][Ktot k];
// conv weights at k=0..Kcnv-1.
__global__ void k_cvtW(const float* __restrict__ W, _Float16* __restrict__ WhT,
                       _Float16* __restrict__ WlT, int Kcnv, int Ktot)
{
  int idx = blockIdx.x*blockDim.x + threadIdx.x;
  if(idx >= 64*Kcnv) return;
  int o = idx / Kcnv, k = idx - o*Kcnv;
  float w = W[(size_t)k*64 + o];
  _Float16 h = (_Float16)w;
  WhT[(size_t)o*Ktot + k] = h;
  WlT[(size_t)o*Ktot + k] = (_Float16)(w - (float)h);
}

// ---- dense-weight append: dW[cin][64] -> WhT/WlT rows k = koff..koff+Kcin-1 (fusion).
__global__ void k_cvtWd(const float* __restrict__ dW, _Float16* __restrict__ WhT,
                        _Float16* __restrict__ WlT, int Kcin, int Ktot, int koff)
{
  int idx = blockIdx.x*blockDim.x + threadIdx.x;
  if(idx >= 64*Kcin) return;
  int o = idx / Kcin, c = idx - o*Kcin;
  float w = dW[(size_t)c*64 + o];
  _Float16 h = (_Float16)w;
  WhT[(size_t)o*Ktot + koff + c] = h;
  WlT[(size_t)o*Ktot + koff + c] = (_Float16)(w - (float)h);
}

// ---- MFMA GEMM: M=64 tile, packed pre-split A. Kd = TOTAL K (conv cells + fused dense).
__global__ __launch_bounds__(256) void k_gemm_mfma(
    const unsigned* __restrict__ Ap, const _Float16* __restrict__ WhT,
    const _Float16* __restrict__ WlT, float* __restrict__ P,
    int M, int Kd, int node_base, int ksteps_per)
{
  __shared__ __align__(128) _Float16 Ah[64*32];
  __shared__ __align__(128) _Float16 Al[64*32];
  __shared__ __align__(128) _Float16 Bh[64*32];
  __shared__ __align__(128) _Float16 Blo[64*32];
  const int tid = threadIdx.x;
  const int mbase = blockIdx.x * 64;
  const int s = blockIdx.y;
  const int kt0 = s * ksteps_per * 32;
  const int kt1 = min(Kd, kt0 + ksteps_per*32);
  const int wv = tid >> 6, lane = tid & 63;
  const int row  = tid >> 2;          // staging row (A row / W col), 0..63
  const int useg = (tid & 3) * 8;     // u32 seg (8 u32 per thread) within 32-wide tile
  const int sb   = (tid & 3) << 4;    // staging byte col (16B per thread per buf)
  const int frow = lane & 15;
  const int fb   = (lane >> 4) << 4;  // frag byte col

  floatx4 acc[4];
  #pragma unroll
  for(int c=0;c<4;++c){ acc[c][0]=0.f; acc[c][1]=0.f; acc[c][2]=0.f; acc[c][3]=0.f; }

  const int grow = mbase + row;
  const unsigned* Arow = (grow < M) ? (Ap + (size_t)grow*Kd) : nullptr;
  const _Float16* WhRow = WhT + (size_t)row*Kd;
  const _Float16* WlRow = WlT + (size_t)row*Kd;

  for(int kt = kt0; kt < kt1; kt += 32){
    unsigned au[8];
    if(Arow){
      *(uint4*)&au[0] = *(const uint4*)(Arow + kt + useg);
      *(uint4*)&au[4] = *(const uint4*)(Arow + kt + useg + 4);
    } else {
      #pragma unroll
      for(int j=0;j<8;++j) au[j] = 0u;
    }
    half8_t hv, lv;
    #pragma unroll
    for(int j=0;j<8;++j){
      hv[j] = lo16(au[j]);
      lv[j] = hi16(au[j]);
    }
    half8_t wh = *(const half8_t*)(WhRow + kt + useg);
    half8_t wl = *(const half8_t*)(WlRow + kt + useg);
    __syncthreads();                        // previous iter's frag reads complete
    *(half8_t*)swzp(Ah,  (row<<6) + sb) = hv;
    *(half8_t*)swzp(Al,  (row<<6) + sb) = lv;
    *(half8_t*)swzp(Bh,  (row<<6) + sb) = wh;
    *(half8_t*)swzp(Blo, (row<<6) + sb) = wl;
    __syncthreads();                        // staged tile visible
    const half8_t ah = *(const half8_t*)swzp(Ah, ((wv*16 + frow)<<6) + fb);
    const half8_t al = *(const half8_t*)swzp(Al, ((wv*16 + frow)<<6) + fb);
    #pragma unroll
    for(int c=0;c<4;++c){
      const half8_t bh = *(const half8_t*)swzp(Bh,  ((c*16 + frow)<<6) + fb);
      const half8_t bl = *(const half8_t*)swzp(Blo, ((c*16 + frow)<<6) + fb);
      acc[c] = __builtin_amdgcn_mfma_f32_16x16x32_f16(ah, bh, acc[c], 0, 0, 0);
      acc[c] = __builtin_amdgcn_mfma_f32_16x16x32_f16(al, bh, acc[c], 0, 0, 0);
      acc[c] = __builtin_amdgcn_mfma_f32_16x16x32_f16(ah, bl, acc[c], 0, 0, 0);
    }
  }

  const int prow0 = mbase + wv*16 + (lane>>4)*4;
  const int pcol  = lane & 15;
  #pragma unroll
  for(int c=0;c<4;++c){
    #pragma unroll
    for(int r=0;r<4;++r){
      const int rr = prow0 + r;
      if(rr < M)
        P[((size_t)s*NPTS + node_base + rr)*64 + c*16 + pcol] = acc[c][r];
    }
  }
}

// ---- combine partials + FUSED cvtF: x[node*ldout+colofs+o] += sum_s P[s][node][o];
// also emits Fp[node*fpld + colofs + o] = packf(relu(final)) (r19: deletes 3 k_cvtF
// passes; identical fp32 input to the same deterministic pack -> bit-identical).
template<int S>
__global__ void k_combine(const float* __restrict__ P, float* __restrict__ x,
                          int ldout, int colofs, unsigned* __restrict__ Fp, int fpld)
{
  int idx = blockIdx.x*blockDim.x + threadIdx.x;
  if(idx >= NPTS*16) return;
  int node = idx >> 4, c4 = (idx & 15) * 4;
  float4 s = *(const float4*)(P + (size_t)node*64 + c4);
  #pragma unroll
  for(int k=1;k<S;++k){
    float4 t = *(const float4*)(P + ((size_t)k*NPTS + node)*64 + c4);
    s.x+=t.x; s.y+=t.y; s.z+=t.z; s.w+=t.w;
  }
  float* xp = x + (size_t)node*ldout + colofs + c4;
  float4 o = *(float4*)xp;
  o.x+=s.x; o.y+=s.y; o.z+=s.z; o.w+=s.w;
  *(float4*)xp = o;
  uint4 p;
  p.x = packf(fmaxf(o.x, 0.f));
  p.y = packf(fmaxf(o.y, 0.f));
  p.z = packf(fmaxf(o.z, 0.f));
  p.w = packf(fmaxf(o.w, 0.f));
  *(uint4*)(Fp + (size_t)node*fpld + colofs + c4) = p;
}

// ---------------- dense/bias paths ----------------
// k_dense0 also emits packed relu for its FINAL cols 64..95 (conv never touches them).
__global__ void k_dense0(const float* __restrict__ f, const float* __restrict__ dW,
                         const float* __restrict__ db, const float* __restrict__ cb0,
                         float* __restrict__ out, unsigned* __restrict__ Fp0)
{
  int idx = blockIdx.x*blockDim.x + threadIdx.x;
  if(idx >= NPTS*96) return;
  int i = idx/96, c = idx - i*96;
  if(c < 64){ out[idx] = cb0[c]; return; }
  int o = c - 64;
  float s = db[o];
  const float* row = f + (size_t)i*13;
  #pragma unroll
  for(int j=0;j<13;++j) s = fmaf(row[j], dW[j*32+o], s);
  out[idx] = s;
  Fp0[idx] = packf(fmaxf(s, 0.f));
}

// bias init (dense matvec now fused into the GEMM K): x = db + cb (+ resid)
__global__ void k_bias(const float* __restrict__ db, const float* __restrict__ cb,
                       const float* __restrict__ resid, float* __restrict__ out)
{
  int idx = blockIdx.x*blockDim.x + threadIdx.x;
  if(idx >= NPTS*64) return;
  int o = idx & 63;
  float s = db[o] + cb[o];
  if(resid) s += resid[idx];
  out[idx] = s;
}

__global__ void k_dense3(const float* __restrict__ x2, const float* __restrict__ dW,
                         const float* __restrict__ db, const float* __restrict__ cb,
                         float* __restrict__ out)
{
  int idx = blockIdx.x*blockDim.x + threadIdx.x;
  if(idx >= NREAL*3) return;
  int i = idx/3, o = idx - i*3;
  float s = db[o] + cb[o];
  const float* row = x2 + (size_t)i*64;
  for(int c=0;c<64;++c) s = fmaf(fmaxf(row[c],0.f), dW[c*3+o], s);
  out[idx] = s * (1.f/128.f);
}

// ---------------- host ----------------
static inline size_t alup(size_t x){ return (x + 255) & ~(size_t)255; }

static inline int calc_rows(size_t bcap, int u32row, int want){
  size_t perrow = (size_t)u32row * 4;
  size_t r = (perrow > 0) ? bcap / perrow : 0;
  if(r >= (size_t)want) return want;
  r = (r / 128) * 128;
  if(r < 128) r = 128;
  return (int)r;
}

extern "C" void kernel_launch(void* const* d_in, const int* in_sizes, int n_in,
                              void* d_out, int out_size, void* d_ws, size_t ws_size,
                              hipStream_t stream)
{
  const float* pos   = (const float*)d_in[0];
  const float* feats = (const float*)d_in[1];
  const int*   esrc  = (const int*)d_in[2];
  const int*   edst  = (const int*)d_in[3];
  const float* c0w = (const float*)d_in[4];
  const float* c0b = (const float*)d_in[5];
  const float* d0w = (const float*)d_in[6];
  const float* d0b = (const float*)d_in[7];
  const float* c1w = (const float*)d_in[8];
  const float* c1b = (const float*)d_in[9];
  const float* d1w = (const float*)d_in[10];
  const float* d1b = (const float*)d_in[11];
  const float* c2w = (const float*)d_in[12];
  const float* c2b = (const float*)d_in[13];
  const float* d2w = (const float*)d_in[14];
  const float* d2b = (const float*)d_in[15];
  const float* c3w = (const float*)d_in[16];
  const float* c3b = (const float*)d_in[17];
  const float* d3w = (const float*)d_in[18];
  const float* d3b = (const float*)d_in[19];
  float* out = (float*)d_out;

  char* w = (char*)d_ws;
  size_t off = 0;
  float* f  = (float*)(w+off); off += alup((size_t)NPTS*13*4);
  float* x0 = (float*)(w+off); off += alup((size_t)NPTS*96*4);
  float* x1 = (float*)(w+off); off += alup((size_t)NPTS*64*4);
  float* x2 = (float*)(w+off); off += alup((size_t)NPTS*64*4);
  int* row_start = (int*)(w+off); off += alup((size_t)(NPTS+1)*4);
  int* ereal = (int*)(w+off);     off += alup(16);
  float4* gw = (float4*)(w+off);  off += alup((size_t)EPAD*16);     // per-edge xy weights
  int4*  gmz = (int4*)(w+off);    off += alup((size_t)EPAD*16);     // per-edge zA+cells+dst
  float* P  = (float*)(w+off); off += alup((size_t)8*NPTS*64*4);    // split-K partials
  _Float16* whT = (_Float16*)(w+off); off += alup((size_t)64*6400*2); // W hi (transposed, Ktot<=6240)
  _Float16* wlT = (_Float16*)(w+off); off += alup((size_t)64*6400*2); // W lo (transposed)
  unsigned* Fp0 = (unsigned*)(w+off); off += alup((size_t)NPTS*96*4); // packed pre-split feats (96ch)
  unsigned* Fp1 = (unsigned*)(w+off); off += alup((size_t)NPTS*64*4); // packed relu(x1)
  unsigned* Fp2 = (unsigned*)(w+off); off += alup((size_t)NPTS*64*4); // packed relu(x2)
  unsigned* B = (unsigned*)(w+off);                                   // packed pre-split B
  size_t bcap = (ws_size > off) ? (ws_size - off) : 0;

  k_find_ereal<<<1,1,0,stream>>>(edst, ereal);
  k_csr<<<(NPTS+1+255)/256,256,0,stream>>>(esrc, ereal, row_start);
  k_build_f<<<(NPTS*13+255)/256,256,0,stream>>>(feats, f);
  k_geom<<<(EPAD+255)/256,256,0,stream>>>(pos, esrc, edst, gw, gmz);

  // ---- layer 0: x0[:,0:64] = cconv0(f)+c0b ; x0[:,64:96] = f@d0w+d0b  (chunk 8192)
  // split-K 4 (ktiles_per=7 covers 26 ksteps; dropped splits only wrote +0 -> exact).
  k_dense0<<<(NPTS*96+255)/256,256,0,stream>>>(f, d0w, d0b, c0b, x0, Fp0);
  {
    k_cvtW<<<(64*832+255)/256,256,0,stream>>>(c0w, whT, wlT, 832, 832);
    int rows = calc_rows(bcap, 832, 8192);
    for(int base = 0; base < NPTS; base += rows){
      int m = (NPTS - base < rows) ? (NPTS - base) : rows;
      k_scat13<<<m,128,0,stream>>>(f, gw, gmz, row_start, B, base);
      k_gemm_mfma<<<dim3((m+63)/64, 4),256,0,stream>>>(B, whT, wlT, P, m, 832, base, 7);
    }
    k_combine<4><<<(NPTS*16+255)/256,256,0,stream>>>(P, x0, 96, 0, Fp0, 96);
  }

  // ---- layer 1: x1 = cconv1(relu(x0)) + relu(x0)@d1w + d1b + c1b
  //      dense fused into GEMM: Kd = 6144 + 96; Fp0 produced by dense0+combine (fused cvtF)
  k_bias<<<(NPTS*64+255)/256,256,0,stream>>>(d1b, c1b, nullptr, x1);
  {
    k_cvtW<<<(64*6144+255)/256,256,0,stream>>>(c1w, whT, wlT, 6144, 6240);
    k_cvtWd<<<(64*96+255)/256,256,0,stream>>>(d1w, whT, wlT, 96, 6240, 6144);
    int rows = calc_rows(bcap, 6240, 4096);
    for(int base = 0; base < NPTS; base += rows){
      int m = (NPTS - base < rows) ? (NPTS - base) : rows;
      k_scat96m<<<m,256,0,stream>>>(Fp0, gw, gmz, row_start, B, base);
      k_gemm_mfma<<<dim3((m+63)/64, 8),256,0,stream>>>(B, whT, wlT, P, m, 6240, base, 25);
    }
    k_combine<8><<<(NPTS*16+255)/256,256,0,stream>>>(P, x1, 64, 0, Fp1, 64);
  }

  // ---- layer 2: x2 = cconv2(relu(x1)) + relu(x1)@d2w + d2b + c2b + x1
  //      dense fused into GEMM: Kd = 4096 + 64; Fp1 produced by layer-1 combine
  k_bias<<<(NPTS*64+255)/256,256,0,stream>>>(d2b, c2b, x1, x2);
  {
    k_cvtW<<<(64*4096+255)/256,256,0,stream>>>(c2w, whT, wlT, 4096, 4160);
    k_cvtWd<<<(64*64+255)/256,256,0,stream>>>(d2w, whT, wlT, 64, 4160, 4096);
    int rows = calc_rows(bcap, 4160, 4096);
    for(int base = 0; base < NPTS; base += rows){
      int m = (NPTS - base < rows) ? (NPTS - base) : rows;
      k_scat64m<0><<<m,256,0,stream>>>(Fp1, gw, gmz, row_start, B, base, nullptr, nullptr);
      k_gemm_mfma<<<dim3((m+63)/64, 8),256,0,stream>>>(B, whT, wlT, P, m, 4160, base, 17);
    }
    k_combine<8><<<(NPTS*16+255)/256,256,0,stream>>>(P, x2, 64, 0, Fp2, 64);
  }

  // ---- layer 3 (fused): out = dense3 part, then scatter adds conv3 GEMV directly
  //      Fp2 produced by layer-2 combine (fused cvtF)
  k_dense3<<<(NREAL*3+255)/256,256,0,stream>>>(x2, d3w, d3b, c3b, out);
  k_scat64m<1><<<NPTS,256,0,stream>>>(Fp2, gw, gmz, row_start, nullptr, 0, c3w, out);
}

// Round 21
// 869.069 us; speedup vs baseline: 1.0252x; 1.0040x over previous
//
#include <hip/hip_runtime.h>
#include <math.h>

#define NPTS   20001
#define NREAL  20000
#define EPAD   1200000
#define KK     64
#define RADF   0.1125f

typedef _Float16 half8_t __attribute__((ext_vector_type(8)));
typedef float    floatx4 __attribute__((ext_vector_type(4)));

__device__ __forceinline__ float sgnf(float v){ return v>0.f ? 1.f : (v<0.f ? -1.f : 0.f); }
__device__ __forceinline__ _Float16 lo16(unsigned u){ return __builtin_bit_cast(_Float16, (unsigned short)(u & 0xffffu)); }
__device__ __forceinline__ _Float16 hi16(unsigned u){ return __builtin_bit_cast(_Float16, (unsigned short)(u >> 16)); }
// deterministic fp32 -> packed f16 hi/lo split (hi in low 16 bits).
__device__ __forceinline__ unsigned packf(float v){
  _Float16 h = (_Float16)v;
  _Float16 l = (_Float16)(v - (float)h);
  return (unsigned)__builtin_bit_cast(unsigned short, h)
       | ((unsigned)__builtin_bit_cast(unsigned short, l) << 16);
}

// byte-offset XOR swizzle for [rows][32]-half (64B-row) LDS tiles.
__device__ __forceinline__ void* swzp(void* base, int byteoff){
  return (void*)((char*)base + (byteoff ^ (((byteoff >> 6) & 7) << 4)));
}
__device__ __forceinline__ const void* swzp(const void* base, int byteoff){
  return (const void*)((const char*)base + (byteoff ^ (((byteoff >> 6) & 7) << 4)));
}

// ---------------- CSR build (edge_src is sorted; pad edges have dst==NREAL) ----------------
__global__ void k_find_ereal(const int* __restrict__ dst, int* __restrict__ ereal){
  int lo=0, hi=EPAD;
  while(lo<hi){ int mid=(lo+hi)>>1; if(dst[mid]==NREAL) hi=mid; else lo=mid+1; }
  *ereal = lo;
}

__global__ void k_csr(const int* __restrict__ src, const int* __restrict__ erealp,
                      int* __restrict__ row_start){
  int i = blockIdx.x*blockDim.x + threadIdx.x;
  if(i > NPTS) return;
  int E = *erealp;
  int lo=0, hi=E;
  while(lo<hi){ int mid=(lo+hi)>>1; if(src[mid] < i) lo=mid+1; else hi=mid; }
  row_start[i] = lo;
}

__global__ void k_build_f(const float* __restrict__ feats, float* __restrict__ f){
  int idx = blockIdx.x*blockDim.x + threadIdx.x;
  if(idx >= NPTS*13) return;
  int i = idx/13, c = idx - i*13;
  f[idx] = (c==0) ? 1.f : feats[i*12 + (c-1)];
}

// ---------------- per-edge geometry (exact port of ball_to_cube + window) ----------------
__device__ __forceinline__ void edge_geom(float ox, float oy, float oz,
                                          float& win, float& t0, float& t1, float& t2, int& f0p){
  const float eps = 1e-9f;
  float sq = ox*ox + oy*oy + oz*oz;
  float u = 1.f - sq;
  win = fminf(fmaxf(u*u*u, 0.f), 1.f);
  float norm = sqrtf(sq + eps);
  float rxy2 = ox*ox + oy*oy;
  bool polar = (1.25f*oz*oz > rxy2);
  float s_p = sqrtf(3.f*norm/(norm + fabsf(oz) + eps));
  float s_n = norm / sqrtf(rxy2 + eps);
  float s = polar ? s_p : s_n;
  float xc = ox*s, yc = oy*s;
  float zc = polar ? sgnf(oz)*norm : 1.5f*oz;
  if(sq < 1e-12f){ xc = 0.f; yc = 0.f; zc = 0.f; }
  float r = sqrtf(xc*xc + yc*yc + eps);
  bool c1 = fabsf(xc) >= fabsf(yc);
  float xs = (fabsf(xc) < eps) ? eps : xc;
  float ys = (fabsf(yc) < eps) ? eps : yc;
  const float fop = 1.2732395447351628f; // float32(4/pi)
  float a = c1 ? sgnf(xc)*r : sgnf(yc)*r*fop*atanf(xc/ys);
  float b = c1 ? sgnf(xc)*r*fop*atanf(yc/xs) : sgnf(yc)*r;
  if(xc*xc + yc*yc < 1e-12f){ a = 0.f; b = 0.f; }
  float g0 = fminf(fmaxf((a *0.5f+0.5f)*3.f, 0.f), 3.f);
  float g1 = fminf(fmaxf((b *0.5f+0.5f)*3.f, 0.f), 3.f);
  float g2 = fminf(fmaxf((zc*0.5f+0.5f)*3.f, 0.f), 3.f);
  float f00 = floorf(g0), f01 = floorf(g1), f02 = floorf(g2);
  t0 = g0 - f00; t1 = g1 - f01; t2 = g2 - f02;
  f0p = (int)f00 | ((int)f01 << 2) | ((int)f02 << 4);
}

// ---- k_geom: per-edge staged data, computed ONCE (shared by all 4 scatter layers).
__global__ __launch_bounds__(256) void k_geom(const float* __restrict__ pos,
    const int* __restrict__ esrc, const int* __restrict__ edst,
    float4* __restrict__ gw, int4* __restrict__ gmz)
{
  int e = blockIdx.x*blockDim.x + threadIdx.x;
  if(e >= EPAD) return;
  const int sn = esrc[e], d = edst[e];
  const float ox = (pos[d*3+0]-pos[sn*3+0])/RADF;
  const float oy = (pos[d*3+1]-pos[sn*3+1])/RADF;
  const float oz = (pos[d*3+2]-pos[sn*3+2])/RADF;
  float win, t0, t1, t2; int f0p;
  edge_geom(ox, oy, oz, win, t0, t1, t2, f0p);
  const int i0 = f0p & 3, i1 = (f0p>>2) & 3, i2 = f0p >> 4;
  const int X0 = i0 << 4, X1 = ((i0+1)&3) << 4;
  const int Y0 = i1 << 2, Y1 = ((i1+1)&3) << 2;
  const int Z0 = i2, Z1 = (i2+1) & 3;
  const float wx0 = win*(1.f-t0), wx1 = win*t0;
  const float wy0 = 1.f-t1, wy1 = t1;
  const float wz0 = 1.f-t2, wz1 = t2;
  gw[e] = make_float4(wx0*wy0, wx0*wy1, wx1*wy0, wx1*wy1);
  const int p0 = Z0 & 1;
  const float zA = p0 ? wz1 : wz0;                  // weight for parity-0 (even z) cell
  const int   cA = p0 ? Z1 : Z0;                    // even-z cell
  const int   cB = p0 ? Z0 : Z1;                    // odd-z cell
  const int cells0 = (X0|Y0|cA) | ((X0|Y1|cA)<<8) | ((X1|Y0|cA)<<16) | ((X1|Y1|cA)<<24);
  const int cells1 = (X0|Y0|cB) | ((X0|Y1|cB)<<8) | ((X1|Y0|cB)<<16) | ((X1|Y1|cB)<<24);
  gmz[e] = make_int4(__float_as_int(zA), cells0, cells1, d);
}

// ------- MFMA scatter CIN=64 (v8): dual 32-tiles (r17/r18) + FUSED dense3 epilogue
// (OUT3=1): out = (conv3 GEMV + relu(x2)@d3w + d3b + c3b)/128 in one pure write;
// deletes k_dense3 and the out read-modify-write. Dense value reconstructed from the
// packed pair (hi+lo, rel err ~2^-22, far under tolerance).
template<int OUT3>
__global__ __launch_bounds__(256) void k_scat64m(
    const unsigned* __restrict__ Fp, const float4* __restrict__ gw,
    const int4* __restrict__ gmz, const int* __restrict__ row_start,
    unsigned* __restrict__ B, int node_base,
    const float* __restrict__ W3, const float* __restrict__ D3,
    const float* __restrict__ db3, const float* __restrict__ cb3,
    float* __restrict__ out)
{
  __shared__ __align__(128) _Float16 Wh0[64*32];
  __shared__ __align__(128) _Float16 Wl0[64*32];
  __shared__ __align__(128) _Float16 Wh1[64*32];
  __shared__ __align__(128) _Float16 Wl1[64*32];
  __shared__ __align__(128) _Float16 Fh0[64*32];
  __shared__ __align__(128) _Float16 Fl0[64*32];
  __shared__ __align__(128) _Float16 Fh1[64*32];
  __shared__ __align__(128) _Float16 Fl1[64*32];
  __shared__ __align__(16) float4 Sq[64];
  __shared__ __align__(16) int4   Smd[64];
  __shared__ float red[16];

  const int tid  = threadIdx.x;
  const int node = node_base + blockIdx.x;
  const int wv   = tid >> 6;
  const int lane = tid & 63;
  const int frow = lane & 15;
  const int fb   = (lane >> 4) << 4;   // frag col byte offset

  floatx4 acc[4];
  #pragma unroll
  for(int nt=0;nt<4;++nt){ acc[nt][0]=0.f; acc[nt][1]=0.f; acc[nt][2]=0.f; acc[nt][3]=0.f; }

  half8_t hz;
  #pragma unroll
  for(int q8=0;q8<8;++q8) hz[q8] = (_Float16)0;

  const int e0 = row_start[node], e1 = row_start[node+1];

  for(int eb = e0; eb < e1; eb += 64){
    const int n = (e1 - eb < 64) ? (e1 - eb) : 64;
    __syncthreads();                       // prior frag + Sq/Smd reads complete
    if(wv == 0){
      int ei = eb + lane; if(ei >= e1) ei = e1 - 1;   // clamp tail (scatter guarded by n)
      Sq[lane]  = gw[ei];
      Smd[lane] = gmz[ei];
    } else {
      for(int j = tid - 64; j < 1024; j += 192){
        if(j < 256)       ((half8_t*)Wh0)[j]       = hz;
        else if(j < 512)  ((half8_t*)Wl0)[j - 256] = hz;
        else if(j < 768)  ((half8_t*)Wh1)[j - 512] = hz;
        else              ((half8_t*)Wl1)[j - 768] = hz;
      }
    }
    __syncthreads();                       // Sq/Smd + zeroed Wt visible
    {
      half8_t h0r, l0r, h1r, l1r;
      #pragma unroll
      for(int j=0;j<8;++j){
        const int d0 = Smd[wv*8 + j].w;
        const unsigned u0 = Fp[(size_t)d0*64 + lane];
        h0r[j] = lo16(u0);
        l0r[j] = hi16(u0);
        const int d1 = Smd[32 + wv*8 + j].w;
        const unsigned u1 = Fp[(size_t)d1*64 + lane];
        h1r[j] = lo16(u1);
        l1r[j] = hi16(u1);
      }
      *(half8_t*)swzp(Fh0, (lane<<6) + (wv<<4)) = h0r;
      *(half8_t*)swzp(Fl0, (lane<<6) + (wv<<4)) = l0r;
      *(half8_t*)swzp(Fh1, (lane<<6) + (wv<<4)) = h1r;
      *(half8_t*)swzp(Fl1, (lane<<6) + (wv<<4)) = l1r;
    }
    if(lane < 16){
      const int ei = wv*16 + lane;         // 4 waves x 16 = 64 edges
      if(ei < n){
        const float4 q  = Sq[ei];
        const int4   md = Smd[ei];
        const float zA = __int_as_float(md.x), zB = 1.f - zA;
        _Float16* Whp = (ei < 32) ? Wh0 : Wh1;
        _Float16* Wlp = (ei < 32) ? Wl0 : Wl1;
        const int ep = ei & 31;
        #pragma unroll
        for(int t=0;t<8;++t){
          const int   cells = (t < 4) ? md.y : md.z;
          const float zz    = (t < 4) ? zA : zB;
          const int   cell  = (cells >> ((t & 3) * 8)) & 255;
          const float qq    = ((t&3)==0) ? q.x : ((t&3)==1) ? q.y : ((t&3)==2) ? q.z : q.w;
          const float wgt   = qq * zz;
          const _Float16 h  = (_Float16)wgt;
          *(_Float16*)swzp(Whp, (cell<<6) + (ep<<1)) = h;
          *(_Float16*)swzp(Wlp, (cell<<6) + (ep<<1)) = (_Float16)(wgt - (float)h);
        }
      }
    }
    __syncthreads();                       // both tiles staged
    {
      const half8_t ah = *(const half8_t*)swzp(Wh0, ((wv*16 + frow)<<6) + fb);
      const half8_t al = *(const half8_t*)swzp(Wl0, ((wv*16 + frow)<<6) + fb);
      #pragma unroll
      for(int nt=0; nt<4; ++nt){
        const half8_t bh = *(const half8_t*)swzp(Fh0, ((nt*16 + frow)<<6) + fb);
        const half8_t bl = *(const half8_t*)swzp(Fl0, ((nt*16 + frow)<<6) + fb);
        acc[nt] = __builtin_amdgcn_mfma_f32_16x16x32_f16(ah, bh, acc[nt], 0, 0, 0);
        acc[nt] = __builtin_amdgcn_mfma_f32_16x16x32_f16(al, bh, acc[nt], 0, 0, 0);
        acc[nt] = __builtin_amdgcn_mfma_f32_16x16x32_f16(ah, bl, acc[nt], 0, 0, 0);
      }
    }
    {
      const half8_t ah = *(const half8_t*)swzp(Wh1, ((wv*16 + frow)<<6) + fb);
      const half8_t al = *(const half8_t*)swzp(Wl1, ((wv*16 + frow)<<6) + fb);
      #pragma unroll
      for(int nt=0; nt<4; ++nt){
        const half8_t bh = *(const half8_t*)swzp(Fh1, ((nt*16 + frow)<<6) + fb);
        const half8_t bl = *(const half8_t*)swzp(Fl1, ((nt*16 + frow)<<6) + fb);
        acc[nt] = __builtin_amdgcn_mfma_f32_16x16x32_f16(ah, bh, acc[nt], 0, 0, 0);
        acc[nt] = __builtin_amdgcn_mfma_f32_16x16x32_f16(al, bh, acc[nt], 0, 0, 0);
        acc[nt] = __builtin_amdgcn_mfma_f32_16x16x32_f16(ah, bl, acc[nt], 0, 0, 0);
      }
    }
  }

  if(!OUT3){
    unsigned* Bg = B + (size_t)blockIdx.x*4160;
    #pragma unroll
    for(int nt=0;nt<4;++nt)
      #pragma unroll
      for(int r=0;r<4;++r){
        const int cell = wv*16 + (lane>>4)*4 + r;
        Bg[cell*64 + nt*16 + (lane&15)] = packf(acc[nt][r]);
      }
    if(tid < 64) Bg[4096 + tid] = Fp[(size_t)node*64 + tid];
  } else {
    float s0=0.f, s1=0.f, s2=0.f;
    #pragma unroll
    for(int nt=0;nt<4;++nt){
      #pragma unroll
      for(int r=0;r<4;++r){
        const int cell = wv*16 + (lane>>4)*4 + r;
        const int j3   = (cell*64 + nt*16 + (lane&15)) * 3;
        const float v  = acc[nt][r];
        s0 = fmaf(v, W3[j3+0], s0);
        s1 = fmaf(v, W3[j3+1], s1);
        s2 = fmaf(v, W3[j3+2], s2);
      }
    }
    // fused dense3: threads tid<64 add relu(x2[node][tid]) * d3w[tid][0..2]
    if(tid < 64){
      const unsigned u = Fp[(size_t)node*64 + tid];
      const float v = (float)lo16(u) + (float)hi16(u);
      const int j3 = tid*3;
      s0 = fmaf(v, D3[j3+0], s0);
      s1 = fmaf(v, D3[j3+1], s1);
      s2 = fmaf(v, D3[j3+2], s2);
    }
    #pragma unroll
    for(int off = 32; off > 0; off >>= 1){
      s0 += __shfl_down(s0, off);
      s1 += __shfl_down(s1, off);
      s2 += __shfl_down(s2, off);
    }
    if(lane == 0){
      red[wv*4+0] = s0; red[wv*4+1] = s1; red[wv*4+2] = s2;
    }
    __syncthreads();
    if(tid == 0 && node < NREAL){
      out[node*3+0] = (red[0]+red[4]+red[8] +red[12] + db3[0]+cb3[0])*(1.f/128.f);
      out[node*3+1] = (red[1]+red[5]+red[9] +red[13] + db3[1]+cb3[1])*(1.f/128.f);
      out[node*3+2] = (red[2]+red[6]+red[10]+red[14] + db3[2]+cb3[2])*(1.f/128.f);
    }
  }
}

// ------- MFMA scatter CIN=96 (r17-measured single-tile form) -------------------------------
__global__ __launch_bounds__(256) void k_scat96m(
    const unsigned* __restrict__ Fp, const float4* __restrict__ gw,
    const int4* __restrict__ gmz, const int* __restrict__ row_start,
    unsigned* __restrict__ B, int node_base)
{
  __shared__ __align__(128) _Float16 Wh[64*32];
  __shared__ __align__(128) _Float16 Wl[64*32];
  __shared__ __align__(128) _Float16 Fh[96*32];
  __shared__ __align__(128) _Float16 Fl[96*32];
  __shared__ __align__(16) float4 Sq[32];
  __shared__ __align__(16) int4   Smd[32];

  const int tid  = threadIdx.x;
  const int node = node_base + blockIdx.x;
  const int wv   = tid >> 6;
  const int lane = tid & 63;
  const int frow = lane & 15;
  const int fb   = (lane >> 4) << 4;

  floatx4 acc[6];
  #pragma unroll
  for(int nt=0;nt<6;++nt){ acc[nt][0]=0.f; acc[nt][1]=0.f; acc[nt][2]=0.f; acc[nt][3]=0.f; }

  half8_t hz;
  #pragma unroll
  for(int q8=0;q8<8;++q8) hz[q8] = (_Float16)0;

  const int e0 = row_start[node], e1 = row_start[node+1];

  for(int eb = e0; eb < e1; eb += 32){
    const int n = (e1 - eb < 32) ? (e1 - eb) : 32;
    __syncthreads();
    if(wv == 0){
      if(lane < 32){
        int ei = eb + lane; if(ei >= e1) ei = e1 - 1;
        Sq[lane]  = gw[ei];
        Smd[lane] = gmz[ei];
      }
    } else {
      for(int j = tid - 64; j < 512; j += 192){
        if(j < 256) ((half8_t*)Wh)[j]       = hz;
        else        ((half8_t*)Wl)[j - 256] = hz;
      }
    }
    __syncthreads();
    {
      half8_t h0, l0, h1, l1;
      #pragma unroll
      for(int j=0;j<8;++j){
        const int dst = Smd[wv*8 + j].w;
        const unsigned u = Fp[(size_t)dst*96 + lane];
        h0[j] = lo16(u);
        l0[j] = hi16(u);
        if(lane < 32){
          const unsigned u2 = Fp[(size_t)dst*96 + 64 + lane];
          h1[j] = lo16(u2);
          l1[j] = hi16(u2);
        }
      }
      *(half8_t*)swzp(Fh, (lane<<6) + (wv<<4)) = h0;
      *(half8_t*)swzp(Fl, (lane<<6) + (wv<<4)) = l0;
      if(lane < 32){
        *(half8_t*)swzp(Fh, ((64+lane)<<6) + (wv<<4)) = h1;
        *(half8_t*)swzp(Fl, ((64+lane)<<6) + (wv<<4)) = l1;
      }
    }
    if(lane < 8){
      const int ei = wv*8 + lane;
      if(ei < n){
        const float4 q  = Sq[ei];
        const int4   md = Smd[ei];
        const float zA = __int_as_float(md.x), zB = 1.f - zA;
        #pragma unroll
        for(int t=0;t<8;++t){
          const int   cells = (t < 4) ? md.y : md.z;
          const float zz    = (t < 4) ? zA : zB;
          const int   cell  = (cells >> ((t & 3) * 8)) & 255;
          const float qq    = ((t&3)==0) ? q.x : ((t&3)==1) ? q.y : ((t&3)==2) ? q.z : q.w;
          const float wgt   = qq * zz;
          const _Float16 h  = (_Float16)wgt;
          *(_Float16*)swzp(Wh, (cell<<6) + (ei<<1)) = h;
          *(_Float16*)swzp(Wl, (cell<<6) + (ei<<1)) = (_Float16)(wgt - (float)h);
        }
      }
    }
    __syncthreads();
    const half8_t ah = *(const half8_t*)swzp(Wh, ((wv*16 + frow)<<6) + fb);
    const half8_t al = *(const half8_t*)swzp(Wl, ((wv*16 + frow)<<6) + fb);
    #pragma unroll
    for(int nt=0; nt<6; ++nt){
      const half8_t bh = *(const half8_t*)swzp(Fh, ((nt*16 + frow)<<6) + fb);
      const half8_t bl = *(const half8_t*)swzp(Fl, ((nt*16 + frow)<<6) + fb);
      acc[nt] = __builtin_amdgcn_mfma_f32_16x16x32_f16(ah, bh, acc[nt], 0, 0, 0);
      acc[nt] = __builtin_amdgcn_mfma_f32_16x16x32_f16(al, bh, acc[nt], 0, 0, 0);
      acc[nt] = __builtin_amdgcn_mfma_f32_16x16x32_f16(ah, bl, acc[nt], 0, 0, 0);
    }
  }

  unsigned* Bg = B + (size_t)blockIdx.x*6240;
  #pragma unroll
  for(int nt=0;nt<6;++nt)
    #pragma unroll
    for(int r=0;r<4;++r){
      const int cell = wv*16 + (lane>>4)*4 + r;
      Bg[cell*96 + nt*16 + (lane&15)] = packf(acc[nt][r]);
    }
  if(tid < 96) Bg[6144 + tid] = Fp[(size_t)node*96 + tid];
}

// ------- scatter CIN=13 (RMW form), packed-B epilogue -------------------------------------
__global__ __launch_bounds__(128) void k_scat13(
    const float* __restrict__ feat, const float4* __restrict__ gw,
    const int4* __restrict__ gmz, const int* __restrict__ row_start,
    unsigned* __restrict__ B, int node_base)
{
  constexpr int CIN = 13, BSZ = KK*CIN, ESW = 4, CSTRIDE = BSZ + 8;
  __shared__ __align__(16) float Bl[ESW*CSTRIDE];
  const int tid  = threadIdx.x;
  const int node = node_base + blockIdx.x;

  for(int j = tid; j < ESW*CSTRIDE; j += 128) Bl[j] = 0.f;

  const int e0 = row_start[node], e1 = row_start[node+1];
  const int wv   = tid >> 6;
  const int lane = tid & 63;
  const int slot = lane >> 4;
  const int c    = lane & 15;
  const bool act = (c < CIN);
  float* Bp = Bl + slot*CSTRIDE;
  __syncthreads();

  if(act){
    for(int e = e0 + slot; e < e1; e += ESW){
      const float4 q  = gw[e];
      const int4   md = gmz[e];
      const float zA = __int_as_float(md.x);
      const float z  = wv ? (1.f - zA) : zA;
      const int   cp = wv ? md.z : md.y;
      float v = feat[(size_t)md.w*CIN + c] * z;
      const int b0 = ( cp        & 255)*CIN + c;
      const int b1 = ((cp >> 8)  & 255)*CIN + c;
      const int b2 = ((cp >> 16) & 255)*CIN + c;
      const int b3 = (((unsigned)cp) >> 24)*CIN + c;
      float o0 = Bp[b0], o1 = Bp[b1], o2 = Bp[b2], o3 = Bp[b3];
      o0 = fmaf(q.x, v, o0); o1 = fmaf(q.y, v, o1);
      o2 = fmaf(q.z, v, o2); o3 = fmaf(q.w, v, o3);
      Bp[b0] = o0; Bp[b1] = o1; Bp[b2] = o2; Bp[b3] = o3;
    }
  }
  __syncthreads();

  unsigned* Bg = B + (size_t)blockIdx.x*BSZ;
  for(int j = tid*4; j < BSZ; j += 512){
    float4 a = *(const float4*)&Bl[j];
    #pragma unroll
    for(int k = 1; k < ESW; ++k){
      const float4 t = *(const float4*)&Bl[k*CSTRIDE + j];
      a.x += t.x; a.y += t.y; a.z += t.z; a.w += t.w;
    }
    uint4 o;
    o.x = packf(a.x); o.y = packf(a.y); o.z = packf(a.z); o.w = packf(a.w);
    *(uint4*)&Bg[j] = o;
  }
}

// ---- W pre-pass: transpose + split fp32 -> f16 hi/lo. WhT/WlT layout [64 cols][Ktot k];
// conv weights at k=0..Kcnv-1.
__global__ void k_cvtW(const float* __restrict__ W, _Float16* __restrict__ WhT,
                       _Float16* __restrict__ WlT, int Kcnv, int Ktot)
{
  int idx = blockIdx.x*blockDim.x + threadIdx.x;
  if(idx >= 64*Kcnv) return;
  int o = idx / Kcnv, k = idx - o*Kcnv;
  float w = W[(size_t)k*64 + o];
  _Float16 h = (_Float16)w;
  WhT[(size_t)o*Ktot + k] = h;
  WlT[(size_t)o*Ktot + k] = (_Float16)(w - (float)h);
}

// ---- dense-weight append: dW[cin][64] -> WhT/WlT rows k = koff..koff+Kcin-1 (fusion).
__global__ void k_cvtWd(const float* __restrict__ dW, _Float16* __restrict__ WhT,
                        _Float16* __restrict__ WlT, int Kcin, int Ktot, int koff)
{
  int idx = blockIdx.x*blockDim.x + threadIdx.x;
  if(idx >= 64*Kcin) return;
  int o = idx / Kcin, c = idx - o*Kcin;
  float w = dW[(size_t)c*64 + o];
  _Float16 h = (_Float16)w;
  WhT[(size_t)o*Ktot + koff + c] = h;
  WlT[(size_t)o*Ktot + koff + c] = (_Float16)(w - (float)h);
}

// ---- MFMA GEMM: M=64 tile, packed pre-split A. Kd = TOTAL K (conv cells + fused dense).
__global__ __launch_bounds__(256) void k_gemm_mfma(
    const unsigned* __restrict__ Ap, const _Float16* __restrict__ WhT,
    const _Float16* __restrict__ WlT, float* __restrict__ P,
    int M, int Kd, int node_base, int ksteps_per)
{
  __shared__ __align__(128) _Float16 Ah[64*32];
  __shared__ __align__(128) _Float16 Al[64*32];
  __shared__ __align__(128) _Float16 Bh[64*32];
  __shared__ __align__(128) _Float16 Blo[64*32];
  const int tid = threadIdx.x;
  const int mbase = blockIdx.x * 64;
  const int s = blockIdx.y;
  const int kt0 = s * ksteps_per * 32;
  const int kt1 = min(Kd, kt0 + ksteps_per*32);
  const int wv = tid >> 6, lane = tid & 63;
  const int row  = tid >> 2;          // staging row (A row / W col), 0..63
  const int useg = (tid & 3) * 8;     // u32 seg (8 u32 per thread) within 32-wide tile
  const int sb   = (tid & 3) << 4;    // staging byte col (16B per thread per buf)
  const int frow = lane & 15;
  const int fb   = (lane >> 4) << 4;  // frag byte col

  floatx4 acc[4];
  #pragma unroll
  for(int c=0;c<4;++c){ acc[c][0]=0.f; acc[c][1]=0.f; acc[c][2]=0.f; acc[c][3]=0.f; }

  const int grow = mbase + row;
  const unsigned* Arow = (grow < M) ? (Ap + (size_t)grow*Kd) : nullptr;
  const _Float16* WhRow = WhT + (size_t)row*Kd;
  const _Float16* WlRow = WlT + (size_t)row*Kd;

  for(int kt = kt0; kt < kt1; kt += 32){
    unsigned au[8];
    if(Arow){
      *(uint4*)&au[0] = *(const uint4*)(Arow + kt + useg);
      *(uint4*)&au[4] = *(const uint4*)(Arow + kt + useg + 4);
    } else {
      #pragma unroll
      for(int j=0;j<8;++j) au[j] = 0u;
    }
    half8_t hv, lv;
    #pragma unroll
    for(int j=0;j<8;++j){
      hv[j] = lo16(au[j]);
      lv[j] = hi16(au[j]);
    }
    half8_t wh = *(const half8_t*)(WhRow + kt + useg);
    half8_t wl = *(const half8_t*)(WlRow + kt + useg);
    __syncthreads();                        // previous iter's frag reads complete
    *(half8_t*)swzp(Ah,  (row<<6) + sb) = hv;
    *(half8_t*)swzp(Al,  (row<<6) + sb) = lv;
    *(half8_t*)swzp(Bh,  (row<<6) + sb) = wh;
    *(half8_t*)swzp(Blo, (row<<6) + sb) = wl;
    __syncthreads();                        // staged tile visible
    const half8_t ah = *(const half8_t*)swzp(Ah, ((wv*16 + frow)<<6) + fb);
    const half8_t al = *(const half8_t*)swzp(Al, ((wv*16 + frow)<<6) + fb);
    #pragma unroll
    for(int c=0;c<4;++c){
      const half8_t bh = *(const half8_t*)swzp(Bh,  ((c*16 + frow)<<6) + fb);
      const half8_t bl = *(const half8_t*)swzp(Blo, ((c*16 + frow)<<6) + fb);
      acc[c] = __builtin_amdgcn_mfma_f32_16x16x32_f16(ah, bh, acc[c], 0, 0, 0);
      acc[c] = __builtin_amdgcn_mfma_f32_16x16x32_f16(al, bh, acc[c], 0, 0, 0);
      acc[c] = __builtin_amdgcn_mfma_f32_16x16x32_f16(ah, bl, acc[c], 0, 0, 0);
    }
  }

  const int prow0 = mbase + wv*16 + (lane>>4)*4;
  const int pcol  = lane & 15;
  #pragma unroll
  for(int c=0;c<4;++c){
    #pragma unroll
    for(int r=0;r<4;++r){
      const int rr = prow0 + r;
      if(rr < M)
        P[((size_t)s*NPTS + node_base + rr)*64 + c*16 + pcol] = acc[c][r];
    }
  }
}

// ---- combine partials + FUSED cvtF: x[node*ldout+colofs+o] += sum_s P[s][node][o];
// also emits Fp[node*fpld + colofs + o] = packf(relu(final)).
template<int S>
__global__ void k_combine(const float* __restrict__ P, float* __restrict__ x,
                          int ldout, int colofs, unsigned* __restrict__ Fp, int fpld)
{
  int idx = blockIdx.x*blockDim.x + threadIdx.x;
  if(idx >= NPTS*16) return;
  int node = idx >> 4, c4 = (idx & 15) * 4;
  float4 s = *(const float4*)(P + (size_t)node*64 + c4);
  #pragma unroll
  for(int k=1;k<S;++k){
    float4 t = *(const float4*)(P + ((size_t)k*NPTS + node)*64 + c4);
    s.x+=t.x; s.y+=t.y; s.z+=t.z; s.w+=t.w;
  }
  float* xp = x + (size_t)node*ldout + colofs + c4;
  float4 o = *(float4*)xp;
  o.x+=s.x; o.y+=s.y; o.z+=s.z; o.w+=s.w;
  *(float4*)xp = o;
  uint4 p;
  p.x = packf(fmaxf(o.x, 0.f));
  p.y = packf(fmaxf(o.y, 0.f));
  p.z = packf(fmaxf(o.z, 0.f));
  p.w = packf(fmaxf(o.w, 0.f));
  *(uint4*)(Fp + (size_t)node*fpld + colofs + c4) = p;
}

// ---------------- dense/bias paths ----------------
// k_dense0 also emits packed relu for its FINAL cols 64..95 (conv never touches them).
__global__ void k_dense0(const float* __restrict__ f, const float* __restrict__ dW,
                         const float* __restrict__ db, const float* __restrict__ cb0,
                         float* __restrict__ out, unsigned* __restrict__ Fp0)
{
  int idx = blockIdx.x*blockDim.x + threadIdx.x;
  if(idx >= NPTS*96) return;
  int i = idx/96, c = idx - i*96;
  if(c < 64){ out[idx] = cb0[c]; return; }
  int o = c - 64;
  float s = db[o];
  const float* row = f + (size_t)i*13;
  #pragma unroll
  for(int j=0;j<13;++j) s = fmaf(row[j], dW[j*32+o], s);
  out[idx] = s;
  Fp0[idx] = packf(fmaxf(s, 0.f));
}

// bias init (dense matvec now fused into the GEMM K): x = db + cb (+ resid)
__global__ void k_bias(const float* __restrict__ db, const float* __restrict__ cb,
                       const float* __restrict__ resid, float* __restrict__ out)
{
  int idx = blockIdx.x*blockDim.x + threadIdx.x;
  if(idx >= NPTS*64) return;
  int o = idx & 63;
  float s = db[o] + cb[o];
  if(resid) s += resid[idx];
  out[idx] = s;
}

// ---------------- host ----------------
static inline size_t alup(size_t x){ return (x + 255) & ~(size_t)255; }

static inline int calc_rows(size_t bcap, int u32row, int want){
  size_t perrow = (size_t)u32row * 4;
  size_t r = (perrow > 0) ? bcap / perrow : 0;
  if(r >= (size_t)want) return want;
  r = (r / 128) * 128;
  if(r < 128) r = 128;
  return (int)r;
}

extern "C" void kernel_launch(void* const* d_in, const int* in_sizes, int n_in,
                              void* d_out, int out_size, void* d_ws, size_t ws_size,
                              hipStream_t stream)
{
  const float* pos   = (const float*)d_in[0];
  const float* feats = (const float*)d_in[1];
  const int*   esrc  = (const int*)d_in[2];
  const int*   edst  = (const int*)d_in[3];
  const float* c0w = (const float*)d_in[4];
  const float* c0b = (const float*)d_in[5];
  const float* d0w = (const float*)d_in[6];
  const float* d0b = (const float*)d_in[7];
  const float* c1w = (const float*)d_in[8];
  const float* c1b = (const float*)d_in[9];
  const float* d1w = (const float*)d_in[10];
  const float* d1b = (const float*)d_in[11];
  const float* c2w = (const float*)d_in[12];
  const float* c2b = (const float*)d_in[13];
  const float* d2w = (const float*)d_in[14];
  const float* d2b = (const float*)d_in[15];
  const float* c3w = (const float*)d_in[16];
  const float* c3b = (const float*)d_in[17];
  const float* d3w = (const float*)d_in[18];
  const float* d3b = (const float*)d_in[19];
  float* out = (float*)d_out;

  char* w = (char*)d_ws;
  size_t off = 0;
  float* f  = (float*)(w+off); off += alup((size_t)NPTS*13*4);
  float* x0 = (float*)(w+off); off += alup((size_t)NPTS*96*4);
  float* x1 = (float*)(w+off); off += alup((size_t)NPTS*64*4);
  float* x2 = (float*)(w+off); off += alup((size_t)NPTS*64*4);
  int* row_start = (int*)(w+off); off += alup((size_t)(NPTS+1)*4);
  int* ereal = (int*)(w+off);     off += alup(16);
  float4* gw = (float4*)(w+off);  off += alup((size_t)EPAD*16);     // per-edge xy weights
  int4*  gmz = (int4*)(w+off);    off += alup((size_t)EPAD*16);     // per-edge zA+cells+dst
  float* P  = (float*)(w+off); off += alup((size_t)8*NPTS*64*4);    // split-K partials
  _Float16* whT = (_Float16*)(w+off); off += alup((size_t)64*6400*2); // W hi (transposed, Ktot<=6240)
  _Float16* wlT = (_Float16*)(w+off); off += alup((size_t)64*6400*2); // W lo (transposed)
  unsigned* Fp0 = (unsigned*)(w+off); off += alup((size_t)NPTS*96*4); // packed pre-split feats (96ch)
  unsigned* Fp1 = (unsigned*)(w+off); off += alup((size_t)NPTS*64*4); // packed relu(x1)
  unsigned* Fp2 = (unsigned*)(w+off); off += alup((size_t)NPTS*64*4); // packed relu(x2)
  unsigned* B = (unsigned*)(w+off);                                   // packed pre-split B
  size_t bcap = (ws_size > off) ? (ws_size - off) : 0;

  k_find_ereal<<<1,1,0,stream>>>(edst, ereal);
  k_csr<<<(NPTS+1+255)/256,256,0,stream>>>(esrc, ereal, row_start);
  k_build_f<<<(NPTS*13+255)/256,256,0,stream>>>(feats, f);
  k_geom<<<(EPAD+255)/256,256,0,stream>>>(pos, esrc, edst, gw, gmz);

  // ---- layer 0: x0[:,0:64] = cconv0(f)+c0b ; x0[:,64:96] = f@d0w+d0b  (chunk 8192)
  // split-K 4 (ktiles_per=7 covers 26 ksteps; dropped splits only wrote +0 -> exact).
  k_dense0<<<(NPTS*96+255)/256,256,0,stream>>>(f, d0w, d0b, c0b, x0, Fp0);
  {
    k_cvtW<<<(64*832+255)/256,256,0,stream>>>(c0w, whT, wlT, 832, 832);
    int rows = calc_rows(bcap, 832, 8192);
    for(int base = 0; base < NPTS; base += rows){
      int m = (NPTS - base < rows) ? (NPTS - base) : rows;
      k_scat13<<<m,128,0,stream>>>(f, gw, gmz, row_start, B, base);
      k_gemm_mfma<<<dim3((m+63)/64, 4),256,0,stream>>>(B, whT, wlT, P, m, 832, base, 7);
    }
    k_combine<4><<<(NPTS*16+255)/256,256,0,stream>>>(P, x0, 96, 0, Fp0, 96);
  }

  // ---- layer 1: x1 = cconv1(relu(x0)) + relu(x0)@d1w + d1b + c1b
  //      dense fused into GEMM: Kd = 6144 + 96; Fp0 produced by dense0+combine (fused cvtF)
  k_bias<<<(NPTS*64+255)/256,256,0,stream>>>(d1b, c1b, nullptr, x1);
  {
    k_cvtW<<<(64*6144+255)/256,256,0,stream>>>(c1w, whT, wlT, 6144, 6240);
    k_cvtWd<<<(64*96+255)/256,256,0,stream>>>(d1w, whT, wlT, 96, 6240, 6144);
    int rows = calc_rows(bcap, 6240, 4096);
    for(int base = 0; base < NPTS; base += rows){
      int m = (NPTS - base < rows) ? (NPTS - base) : rows;
      k_scat96m<<<m,256,0,stream>>>(Fp0, gw, gmz, row_start, B, base);
      k_gemm_mfma<<<dim3((m+63)/64, 8),256,0,stream>>>(B, whT, wlT, P, m, 6240, base, 25);
    }
    k_combine<8><<<(NPTS*16+255)/256,256,0,stream>>>(P, x1, 64, 0, Fp1, 64);
  }

  // ---- layer 2: x2 = cconv2(relu(x1)) + relu(x1)@d2w + d2b + c2b + x1
  //      dense fused into GEMM: Kd = 4096 + 64; Fp1 produced by layer-1 combine
  k_bias<<<(NPTS*64+255)/256,256,0,stream>>>(d2b, c2b, x1, x2);
  {
    k_cvtW<<<(64*4096+255)/256,256,0,stream>>>(c2w, whT, wlT, 4096, 4160);
    k_cvtWd<<<(64*64+255)/256,256,0,stream>>>(d2w, whT, wlT, 64, 4160, 4096);
    int rows = calc_rows(bcap, 4160, 4096);
    for(int base = 0; base < NPTS; base += rows){
      int m = (NPTS - base < rows) ? (NPTS - base) : rows;
      k_scat64m<0><<<m,256,0,stream>>>(Fp1, gw, gmz, row_start, B, base,
                                       nullptr, nullptr, nullptr, nullptr, nullptr);
      k_gemm_mfma<<<dim3((m+63)/64, 8),256,0,stream>>>(B, whT, wlT, P, m, 4160, base, 17);
    }
    k_combine<8><<<(NPTS*16+255)/256,256,0,stream>>>(P, x2, 64, 0, Fp2, 64);
  }

  // ---- layer 3 (fully fused): out = (conv3 GEMV + relu(x2)@d3w + d3b + c3b)/128,
  //      single pure write per node (k_dense3 deleted).
  k_scat64m<1><<<NPTS,256,0,stream>>>(Fp2, gw, gmz, row_start, nullptr, 0,
                                      c3w, d3w, d3b, c3b, out);
}